// Round 11
// baseline (830.998 us; speedup 1.0000x reference)
//
#include <hip/hip_runtime.h>
#include <hip/hip_bf16.h>
#include <cmath>

typedef __bf16 bf16;
typedef __attribute__((ext_vector_type(8))) __bf16 bf16x8;
typedef __attribute__((ext_vector_type(4))) float f32x4;
typedef unsigned int u32;
typedef unsigned short u16;

#define D_MODEL 2048
#define NH 16
#define DQ 128
#define DH 2048
#define DFFN 8192
#define DOUT 22528
#define HQKV 6144
#define BATCH 2
#define SEQ 2048
#define NROWS 4096

__device__ __forceinline__ void gload16(const void* g, void* l) {
    __builtin_amdgcn_global_load_lds((__attribute__((address_space(1))) const void*)g,
                                     (__attribute__((address_space(3))) void*)l, 16, 0, 0);
}

__device__ __forceinline__ float bf2f(u16 u) {
    union { u32 i; float f; } c; c.i = ((u32)u) << 16; return c.f;
}

#define VMW(n)  asm volatile("s_waitcnt vmcnt(" #n ")" ::: "memory")
#define LGK0()  asm volatile("s_waitcnt lgkmcnt(0)" ::: "memory")
#define BARX()  { asm volatile("" ::: "memory"); __builtin_amdgcn_s_barrier(); asm volatile("" ::: "memory"); }

// ---------------- fp32 -> bf16 conversion (plain) ----------------
__global__ __launch_bounds__(256) void cvt_f32_bf16(const float* __restrict__ in,
                                                    bf16* __restrict__ out) {
    size_t i = ((size_t)blockIdx.x * 256 + threadIdx.x) * 8;
    float4 a = *(const float4*)(in + i);
    float4 b = *(const float4*)(in + i + 4);
    bf16x8 o;
    o[0]=(bf16)a.x; o[1]=(bf16)a.y; o[2]=(bf16)a.z; o[3]=(bf16)a.w;
    o[4]=(bf16)b.x; o[5]=(bf16)b.y; o[6]=(bf16)b.z; o[7]=(bf16)b.w;
    *(bf16x8*)(out + i) = o;
}

// ---------------- W_dense conversion with gate-interleave row remap (16-col, proven) ----------------
__global__ __launch_bounds__(256) void cvt_wd(const float* __restrict__ in,
                                              bf16* __restrict__ out) {
    size_t i = ((size_t)blockIdx.x * 256 + threadIdx.x) * 8;
    int nr = (int)(i >> 11);
    int c  = (int)(i & 2047);
    int orig;
    if (nr < HQKV) orig = nr;
    else {
        int gg = nr - HQKV;
        int blk = gg >> 4;
        int f = ((blk >> 1) << 4) + (gg & 15);
        orig = (blk & 1) ? (3*DH + DFFN + f) : (3*DH + f);
    }
    const float* src = in + (size_t)orig * 2048 + c;
    float4 a = *(const float4*)src;
    float4 b = *(const float4*)(src + 4);
    bf16x8 o;
    o[0]=(bf16)a.x; o[1]=(bf16)a.y; o[2]=(bf16)a.z; o[3]=(bf16)a.w;
    o[4]=(bf16)b.x; o[5]=(bf16)b.y; o[6]=(bf16)b.z; o[7]=(bf16)b.w;
    *(bf16x8*)(out + i) = o;
}

// ---------------- RMSNorm (fp32 in -> bf16 out) ----------------
__global__ __launch_bounds__(256) void rmsnorm_k(const float* __restrict__ x,
                                                 const float* __restrict__ g,
                                                 bf16* __restrict__ out) {
    __shared__ float red[4];
    const int row = blockIdx.x;
    const int t = threadIdx.x;
    const float* xr = x + (size_t)row * D_MODEL;
    float4 v0 = *(const float4*)(xr + t*8);
    float4 v1 = *(const float4*)(xr + t*8 + 4);
    float ss = v0.x*v0.x + v0.y*v0.y + v0.z*v0.z + v0.w*v0.w
             + v1.x*v1.x + v1.y*v1.y + v1.z*v1.z + v1.w*v1.w;
    #pragma unroll
    for (int m = 32; m >= 1; m >>= 1) ss += __shfl_xor(ss, m);
    if ((t & 63) == 0) red[t >> 6] = ss;
    __syncthreads();
    float tot = red[0] + red[1] + red[2] + red[3];
    float norm = sqrtf(tot) * 0.022097086912079608f;
    float inv = 1.0f / fmaxf(norm, 1e-8f);
    float4 g0 = *(const float4*)(g + t*8);
    float4 g1 = *(const float4*)(g + t*8 + 4);
    bf16x8 o;
    o[0]=(bf16)(v0.x*inv*g0.x); o[1]=(bf16)(v0.y*inv*g0.y);
    o[2]=(bf16)(v0.z*inv*g0.z); o[3]=(bf16)(v0.w*inv*g0.w);
    o[4]=(bf16)(v1.x*inv*g1.x); o[5]=(bf16)(v1.y*inv*g1.y);
    o[6]=(bf16)(v1.z*inv*g1.z); o[7]=(bf16)(v1.w*inv*g1.w);
    *(bf16x8*)(out + (size_t)row * D_MODEL + t*8) = o;
}

// ---------------- RoPE table ----------------
__global__ __launch_bounds__(256) void rope_table(float* __restrict__ ctab,
                                                  float* __restrict__ stab) {
    int idx = blockIdx.x * 256 + threadIdx.x;
    int l = idx >> 6, i = idx & 63;
    float inv = powf(10000.0f, -(float)i / 64.0f);
    float ang = (float)l * inv;
    float s, c;
    sincosf(ang, &s, &c);
    ctab[idx] = c; stab[idx] = s;
}

// ============ 256x256 dense GEMM (R6 2-buffer fine-phase) + fused bias/SwiGLU ============
#define SLINE_A(c_, t_) \
    gload16(Asrc + (size_t)((c_)*64)*2048 + (size_t)(t_)*64, \
            smem + (((t_)&1)<<16) + (c_)*8192 + wid*1024);
#define SLINE_B(c_, t_) \
    gload16(Bsrc + (size_t)((c_)*64)*2048 + (size_t)(t_)*64, \
            smem + (((t_)&1)<<16) + 32768 + (c_)*8192 + wid*1024);

#define PH_READS_B() \
    _Pragma("unroll") for (int n = 0; n < 4; ++n) { \
        const char* p_ = bb + (wn*64 + n*16 + la) * 128; \
        bfr[n][0] = *(const bf16x8*)(p_ + pg0); \
        bfr[n][1] = *(const bf16x8*)(p_ + pg1); }

#define PH_READS_A(qd_) \
    _Pragma("unroll") for (int mm = 0; mm < 2; ++mm) { \
        const char* p_ = ab + (wm*128 + ((qd_)*2 + mm)*16 + la) * 128; \
        af[mm][0] = *(const bf16x8*)(p_ + pg0); \
        af[mm][1] = *(const bf16x8*)(p_ + pg1); }

#define PH_MFMA(qd_) \
    __builtin_amdgcn_s_setprio(1); \
    _Pragma("unroll") for (int mm = 0; mm < 2; ++mm) \
        _Pragma("unroll") for (int n = 0; n < 4; ++n) { \
            acc[(qd_)*2+mm][n] = __builtin_amdgcn_mfma_f32_16x16x32_bf16(af[mm][0], bfr[n][0], acc[(qd_)*2+mm][n], 0, 0, 0); \
            acc[(qd_)*2+mm][n] = __builtin_amdgcn_mfma_f32_16x16x32_bf16(af[mm][1], bfr[n][1], acc[(qd_)*2+mm][n], 0, 0, 0); } \
    __builtin_amdgcn_s_setprio(0);

__global__ __launch_bounds__(512, 2) void gemm_dense(
    const bf16* __restrict__ A, const bf16* __restrict__ B,
    const float* __restrict__ bias, bf16* __restrict__ h6,
    bf16* __restrict__ ag)
{
    __shared__ char smem[131072];              // 2 buf x [A 32KB | B 32KB]
    const int tid = threadIdx.x;
    const int wid = tid >> 6, lane = tid & 63;
    const int la = lane & 15, hi = lane >> 4;
    const int wm = wid >> 2, wn = wid & 3;

    const int nwg = gridDim.x;                 // 1408
    const int cpx = nwg >> 3;                  // 176
    const int bI = blockIdx.x;
    const int wg = (bI & 7) * cpx + (bI >> 3);
    const int bn = wg >> 4, bm = wg & 15;      // bn-major: W panel L2-resident
    const size_t m0 = (size_t)bm * 256, n0 = (size_t)bn * 256;

    const int lr = lane >> 3, lg = lane & 7;
    const int sg = lg ^ lr;
    const bf16* Asrc = A + (m0 + wid*8 + lr) * (size_t)2048 + sg*8;
    const bf16* Bsrc = B + (n0 + wid*8 + lr) * (size_t)2048 + sg*8;

    const int pg0 = (hi ^ (la & 7)) << 4;
    const int pg1 = ((4 + hi) ^ (la & 7)) << 4;

    f32x4 acc[8][4] = {};
    const int NT = 32;                         // 2048/64

    SLINE_A(0,0); SLINE_A(2,0);
    SLINE_B(0,0); SLINE_B(1,0);
    SLINE_B(2,0); SLINE_B(3,0);
    SLINE_A(1,0); SLINE_A(3,0);
    VMW(2);
    BARX();

    bf16x8 bfr[4][2];
    bf16x8 af[2][2];

    #pragma unroll 1
    for (int t = 0; t < NT - 1; ++t) {
        const char* ab = smem + ((t & 1) << 16);
        const char* bb = ab + 32768;
        const int nx = t + 1;
        PH_READS_B(); PH_READS_A(0);
        SLINE_A(0,nx); SLINE_A(2,nx);
        BARX(); LGK0(); PH_MFMA(0); BARX();
        PH_READS_A(1);
        SLINE_B(0,nx); SLINE_B(1,nx);
        BARX(); LGK0(); PH_MFMA(1); VMW(4); BARX();
        PH_READS_A(2);
        SLINE_B(2,nx); SLINE_B(3,nx);
        BARX(); LGK0(); PH_MFMA(2); BARX();
        PH_READS_A(3);
        SLINE_A(1,nx); SLINE_A(3,nx);
        BARX(); LGK0(); PH_MFMA(3); VMW(2); BARX();
    }
    {
        const int t = NT - 1;
        const char* ab = smem + ((t & 1) << 16);
        const char* bb = ab + 32768;
        PH_READS_B(); PH_READS_A(0);
        BARX(); LGK0(); PH_MFMA(0); BARX();
        PH_READS_A(1);
        BARX(); LGK0(); PH_MFMA(1); VMW(0); BARX();
        PH_READS_A(2);
        BARX(); LGK0(); PH_MFMA(2); BARX();
        PH_READS_A(3);
        BARX(); LGK0(); PH_MFMA(3); BARX();
    }

    if (n0 < HQKV) {
        // qkv region -> h6 [4096, 6144] bf16, +bias
        #pragma unroll
        for (int mf = 0; mf < 8; ++mf) {
            const size_t row = m0 + wm*128 + mf*16 + hi*4;
            #pragma unroll
            for (int nf = 0; nf < 4; ++nf) {
                const size_t col = n0 + wn*64 + nf*16 + la;
                const float bv = bias[col];
                #pragma unroll
                for (int r = 0; r < 4; ++r)
                    h6[(row + r) * HQKV + col] = (bf16)(acc[mf][nf][r] + bv);
            }
        }
    } else {
        // gate region (interleaved a|b 16-col blocks, proven map) -> ag [4096, 8192]
        #pragma unroll
        for (int mf = 0; mf < 8; ++mf) {
            const size_t row = m0 + wm*128 + mf*16 + hi*4;
            #pragma unroll
            for (int np = 0; np < 4; np += 2) {
                const int col_a = (int)n0 + wn*64 + np*16 + la;
                const int gg = col_a - HQKV;
                const int f = ((gg >> 5) << 4) + (gg & 15);
                const float ba = bias[3*DH + f];
                const float bb2 = bias[3*DH + DFFN + f];
                #pragma unroll
                for (int r = 0; r < 4; ++r) {
                    float a = acc[mf][np][r] + ba;
                    float b = acc[mf][np+1][r] + bb2;
                    float sil = b / (1.0f + __expf(-b));
                    ag[(row + r) * (size_t)DFFN + f] = (bf16)(a * sil);
                }
            }
        }
    }
}

// ============ fused epilogue GEMM: out = x + attn.Wa^T + ag.Wf^T (bn-major) ============
#define OSTAGE_A(st_, c_) { \
    const bf16* s_ = (st_) < 32 ? A1s + (size_t)((c_)*64)*2048 + (size_t)(st_)*64 \
                                : A2s + (size_t)((c_)*64)*8192 + (size_t)((st_)-32)*64; \
    gload16(s_, smem + ((st_)%3)*49152 + (c_)*8192 + wid*1024); }
#define OSTAGE_B(st_, c_) { \
    const bf16* s_ = (st_) < 32 ? B1s + (size_t)((c_)*64)*2048 + (size_t)(st_)*64 \
                                : B2s + (size_t)((c_)*64)*8192 + (size_t)((st_)-32)*64; \
    gload16(s_, smem + ((st_)%3)*49152 + 16384 + (c_)*8192 + wid*1024); }

__global__ __launch_bounds__(512, 2) void gemm_out(
    const bf16* __restrict__ A1, const bf16* __restrict__ B1,
    const bf16* __restrict__ A2, const bf16* __restrict__ B2,
    const float* __restrict__ x, float* __restrict__ outf)
{
    __shared__ char smem[147456];
    const int tid = threadIdx.x;
    const int wid = tid >> 6, lane = tid & 63;
    const int la = lane & 15, hi = lane >> 4;
    const int wm = wid >> 2, wn = wid & 3;

    const int nwg = gridDim.x;                 // 256
    const int cpx = nwg >> 3;                  // 32
    const int bI = blockIdx.x;
    const int wg = (bI & 7) * cpx + (bI >> 3);
    const int bm = wg & 31, bn = wg >> 5;      // bn-major: B panel L2-resident per XCD
    const size_t m0 = (size_t)bm * 128, n0 = (size_t)bn * 256;

    const int lr = lane >> 3, lg = lane & 7;
    const int sg = lg ^ lr;
    const bf16* A1s = A1 + (m0 + wid*8 + lr) * (size_t)2048 + sg*8;
    const bf16* A2s = A2 + (m0 + wid*8 + lr) * (size_t)8192 + sg*8;
    const bf16* B1s = B1 + (n0 + wid*8 + lr) * (size_t)2048 + sg*8;
    const bf16* B2s = B2 + (n0 + wid*8 + lr) * (size_t)8192 + sg*8;

    const int pg0 = (hi ^ (la & 7)) << 4;
    const int pg1 = ((4 + hi) ^ (la & 7)) << 4;

    f32x4 acc[4][4] = {};
    const int NT = 160;

    OSTAGE_A(0,0); OSTAGE_A(0,1);
    OSTAGE_B(0,0); OSTAGE_B(0,1); OSTAGE_B(0,2); OSTAGE_B(0,3);
    OSTAGE_A(1,0); OSTAGE_A(1,1);
    OSTAGE_B(1,0); OSTAGE_B(1,1); OSTAGE_B(1,2); OSTAGE_B(1,3);
    VMW(6);
    BARX();

    bf16x8 af[4], bfr[4];
    #pragma unroll 1
    for (int t = 0; t < NT; ++t) {
        const char* ab = smem + (t % 3) * 49152;
        const char* bb = ab + 16384;
        const int st = t + 2;
        #pragma unroll
        for (int m = 0; m < 4; ++m) af[m]  = *(const bf16x8*)(ab + (wm*64 + m*16 + la)*128 + pg0);
        #pragma unroll
        for (int n = 0; n < 4; ++n) bfr[n] = *(const bf16x8*)(bb + (wn*64 + n*16 + la)*128 + pg0);
        if (st < NT) { OSTAGE_A(st,0); OSTAGE_A(st,1); OSTAGE_B(st,0); }
        BARX(); LGK0();
        __builtin_amdgcn_s_setprio(1);
        #pragma unroll
        for (int m = 0; m < 4; ++m)
            #pragma unroll
            for (int n = 0; n < 4; ++n)
                acc[m][n] = __builtin_amdgcn_mfma_f32_16x16x32_bf16(af[m], bfr[n], acc[m][n], 0, 0, 0);
        __builtin_amdgcn_s_setprio(0);
        BARX();
        #pragma unroll
        for (int m = 0; m < 4; ++m) af[m]  = *(const bf16x8*)(ab + (wm*64 + m*16 + la)*128 + pg1);
        #pragma unroll
        for (int n = 0; n < 4; ++n) bfr[n] = *(const bf16x8*)(bb + (wn*64 + n*16 + la)*128 + pg1);
        if (st < NT) { OSTAGE_B(st,1); OSTAGE_B(st,2); OSTAGE_B(st,3); }
        if (t < NT - 2) { VMW(6); } else { VMW(0); }
        BARX(); LGK0();
        __builtin_amdgcn_s_setprio(1);
        #pragma unroll
        for (int m = 0; m < 4; ++m)
            #pragma unroll
            for (int n = 0; n < 4; ++n)
                acc[m][n] = __builtin_amdgcn_mfma_f32_16x16x32_bf16(af[m], bfr[n], acc[m][n], 0, 0, 0);
        __builtin_amdgcn_s_setprio(0);
        BARX();
    }

    #pragma unroll
    for (int mf = 0; mf < 4; ++mf) {
        const size_t row = m0 + wm*64 + mf*16 + hi*4;
        #pragma unroll
        for (int nf = 0; nf < 4; ++nf) {
            const size_t col = n0 + wn*64 + nf*16 + la;
            #pragma unroll
            for (int r = 0; r < 4; ++r) {
                const size_t off = (row + r) * (size_t)DH + col;
                outf[off] = x[off] + acc[mf][nf][r];
            }
        }
    }
}

__device__ __forceinline__ u32 rope_pair(u32 u, float c, float s) {
    float t1 = bf2f((u16)(u & 0xffff));
    float t2 = bf2f((u16)(u >> 16));
    float r1 = t1 * c - t2 * s;
    float r2 = t1 * s + t2 * c;
    bf16 b1 = (bf16)r1, b2 = (bf16)r2;
    return (u32)__builtin_bit_cast(u16, b1) | ((u32)__builtin_bit_cast(u16, b2) << 16);
}

// ---------------- q/k rope + reshape to [B,H,L,128] (h stride 6144) ----------------
__global__ __launch_bounds__(256) void rope_qk(const bf16* __restrict__ h,
                                               const float* __restrict__ ctab,
                                               const float* __restrict__ stab,
                                               bf16* __restrict__ qb, bf16* __restrict__ kb) {
    int idx = blockIdx.x * 256 + threadIdx.x;
    int i  = idx & 63;
    int hh = (idx >> 6) & 15;
    int l  = (idx >> 10) & 2047;
    int b  = idx >> 21;
    size_t hrow = (size_t)(b * SEQ + l) * HQKV;
    float c = ctab[l*64 + i], s = stab[l*64 + i];
    u32 uq = *(const u32*)(h + hrow + hh*DQ + 2*i);
    u32 uk = *(const u32*)(h + hrow + DH + hh*DQ + 2*i);
    size_t orow = ((size_t)(b*NH + hh) * SEQ + l) * DQ + 2*i;
    *(u32*)(qb + orow) = rope_pair(uq, c, s);
    *(u32*)(kb + orow) = rope_pair(uk, c, s);
}

// ---------------- V transpose (h stride 6144) -> vt [B,H,128,L] ----------------
__global__ __launch_bounds__(256) void v_transpose(const bf16* __restrict__ h,
                                                   bf16* __restrict__ vt) {
    __shared__ u32 lds[64][68];
    const int lt = blockIdx.x, bh = blockIdx.y;
    const int b = bh >> 4, hh = bh & 15;
    const int t = threadIdx.x;
    const bf16* src = h + (size_t)(b * SEQ + lt * 64) * HQKV + 2*DH + hh * DQ;
    #pragma unroll
    for (int i = 0; i < 4; ++i) {
        int j = i*256 + t;
        int l = j >> 4, ch = j & 15;
        uint4 v = *(const uint4*)(src + (size_t)l * HQKV + ch*8);
        *(uint4*)&lds[l][ch*4] = v;
    }
    __syncthreads();
    bf16* dst = vt + (size_t)bh * DQ * SEQ + lt * 64;
    #pragma unroll
    for (int i = 0; i < 4; ++i) {
        int j = i*256 + t;
        int d = j >> 3, lc = j & 7;
        u32 out[4];
        #pragma unroll
        for (int m = 0; m < 4; ++m) {
            u32 a0 = lds[lc*8 + 2*m][d >> 1];
            u32 a1 = lds[lc*8 + 2*m + 1][d >> 1];
            u16 s0 = (d & 1) ? (u16)(a0 >> 16) : (u16)(a0 & 0xffff);
            u16 s1 = (d & 1) ? (u16)(a1 >> 16) : (u16)(a1 & 0xffff);
            out[m] = (u32)s0 | ((u32)s1 << 16);
        }
        *(uint4*)(dst + (size_t)d * SEQ + lc*8) = *(uint4*)out;
    }
}

// ---------------- causal flash attention (dbuf K/V, QBLK=128, 8 waves) ----------------
__global__ __launch_bounds__(512, 2) void attn_fa(const bf16* __restrict__ Q,
                                                  const bf16* __restrict__ Kb,
                                                  const bf16* __restrict__ Vt,
                                                  bf16* __restrict__ O) {
    __shared__ char kvs[2][32768];             // [buf][K 16KB | V 16KB]
    __shared__ bf16 Ps[8][16][64];
    const int qt = blockIdx.x, bh = blockIdx.y;
    const int b = bh >> 4, hh = bh & 15;
    const int tid = threadIdx.x, wid = tid >> 6, lane = tid & 63;
    const int la = lane & 15, hi = lane >> 4;
    const bf16* Qp = Q + (size_t)bh * SEQ * DQ;
    const bf16* Kp = Kb + (size_t)bh * SEQ * DQ;
    const bf16* Vp = Vt + (size_t)bh * DQ * SEQ;
    const int q0w = qt * 128 + wid * 16;       // 8 waves x 16 q-rows

    bf16x8 qf[4];
    #pragma unroll
    for (int s = 0; s < 4; ++s)
        qf[s] = *(const bf16x8*)(Qp + (size_t)(q0w + la) * DQ + s*32 + hi*8);

    f32x4 acc_o[8] = {};
    float m_run[4] = {-1e30f, -1e30f, -1e30f, -1e30f};
    float l_run[4] = {0.f, 0.f, 0.f, 0.f};
    const float scale = 0.08838834764831845f;
    const int nk = 2*qt + 2;

// 512 threads: 2 iters cover j=0..1023 (K: 64 rows x 16 granules; V: 128 rows x 8 granules).
// dst byte offset = j*16 (linear), matching gload16's lane*16 dest rule.
#define ATT_STAGE(kt_, buf_) { \
    const int k0_ = (kt_) * 64; \
    _Pragma("unroll") for (int i = 0; i < 2; ++i) { \
        int j = i*512 + tid; \
        int kr = j >> 4, jg = j & 15; \
        gload16(Kp + (size_t)(k0_ + kr) * DQ + ((jg ^ (kr & 7)) << 3), \
                kvs[buf_] + i*8192 + wid*1024); \
        int d = j >> 3, vg = j & 7; \
        gload16(Vp + (size_t)d * SEQ + k0_ + ((vg ^ (d & 7)) << 3), \
                kvs[buf_] + 16384 + i*8192 + wid*1024); \
    } }

    ATT_STAGE(0, 0);

    for (int kt = 0; kt < nk; ++kt) {
        const int k0 = kt * 64;
        const char* kb2 = kvs[kt & 1];
        if (kt + 1 < nk) { ATT_STAGE(kt+1, (kt+1)&1); VMW(4); }
        else             { VMW(0); }
        BARX();

        f32x4 sacc[4] = {};
        __builtin_amdgcn_s_setprio(1);
        #pragma unroll
        for (int g = 0; g < 4; ++g) {
            const int krow = g*16 + la;
            #pragma unroll
            for (int s = 0; s < 4; ++s) {
                bf16x8 kf = *(const bf16x8*)(kb2 + krow*256 + (((s*4 + hi) ^ (la & 7)) << 4));
                sacc[g] = __builtin_amdgcn_mfma_f32_16x16x32_bf16(qf[s], kf, sacc[g], 0, 0, 0);
            }
        }
        __builtin_amdgcn_s_setprio(0);

        float mnew[4];
        #pragma unroll
        for (int r = 0; r < 4; ++r) mnew[r] = m_run[r];
        #pragma unroll
        for (int g = 0; g < 4; ++g)
            #pragma unroll
            for (int r = 0; r < 4; ++r) {
                float sv = sacc[g][r] * scale;
                int qi = q0w + hi*4 + r;
                int ki = k0 + g*16 + la;
                sv = (ki <= qi) ? sv : -1e30f;
                sacc[g][r] = sv;
                mnew[r] = fmaxf(mnew[r], sv);
            }
        #pragma unroll
        for (int r = 0; r < 4; ++r) {
            float v = mnew[r];
            v = fmaxf(v, __shfl_xor(v, 1));
            v = fmaxf(v, __shfl_xor(v, 2));
            v = fmaxf(v, __shfl_xor(v, 4));
            v = fmaxf(v, __shfl_xor(v, 8));
            mnew[r] = v;
        }
        float resc[4], lsum[4];
        #pragma unroll
        for (int r = 0; r < 4; ++r) {
            resc[r] = __expf(m_run[r] - mnew[r]);
            m_run[r] = mnew[r];
            lsum[r] = 0.f;
        }
        #pragma unroll
        for (int g = 0; g < 4; ++g)
            #pragma unroll
            for (int r = 0; r < 4; ++r) {
                float p = __expf(sacc[g][r] - mnew[r]);
                sacc[g][r] = p;
                lsum[r] += p;
            }
        #pragma unroll
        for (int r = 0; r < 4; ++r) {
            float v = lsum[r];
            v += __shfl_xor(v, 1); v += __shfl_xor(v, 2);
            v += __shfl_xor(v, 4); v += __shfl_xor(v, 8);
            l_run[r] = l_run[r] * resc[r] + v;
        }
        #pragma unroll
        for (int g = 0; g < 4; ++g)
            #pragma unroll
            for (int r = 0; r < 4; ++r) {
                int prow = hi*4 + r;
                int pcol = (g*16 + la) ^ ((prow & 7) << 3);
                Ps[wid][prow][pcol] = (bf16)sacc[g][r];
            }
        #pragma unroll
        for (int n = 0; n < 8; ++n)
            #pragma unroll
            for (int r = 0; r < 4; ++r) acc_o[n][r] *= resc[r];
        __builtin_amdgcn_s_setprio(1);
        #pragma unroll
        for (int kk = 0; kk < 2; ++kk) {
            bf16x8 pf = *(const bf16x8*)((const char*)&Ps[wid][0][0] + la*128 +
                                         (((kk*32 + hi*8) ^ ((la & 7) << 3)) << 1));
            #pragma unroll
            for (int n = 0; n < 8; ++n) {
                const int vrow = n*16 + la;
                bf16x8 vf = *(const bf16x8*)(kb2 + 16384 + vrow*128 + (((kk*4 + hi) ^ (la & 7)) << 4));
                acc_o[n] = __builtin_amdgcn_mfma_f32_16x16x32_bf16(pf, vf, acc_o[n], 0, 0, 0);
            }
        }
        __builtin_amdgcn_s_setprio(0);
        BARX();
    }

    bf16* Op = O + (size_t)b * SEQ * DH + (size_t)hh * DQ;
    #pragma unroll
    for (int r = 0; r < 4; ++r) {
        int qi = q0w + hi*4 + r;
        float invl = 1.0f / l_run[r];
        #pragma unroll
        for (int n = 0; n < 8; ++n)
            Op[(size_t)qi * DH + n*16 + la] = (bf16)(acc_o[n][r] * invl);
    }
}

// ---------------- launch ----------------
extern "C" void kernel_launch(void* const* d_in, const int* in_sizes, int n_in,
                              void* d_out, int out_size, void* d_ws, size_t ws_size,
                              hipStream_t stream) {
    const float* x       = (const float*)d_in[0];
    const float* g       = (const float*)d_in[1];
    const float* W_dense = (const float*)d_in[2];
    const float* b_dense = (const float*)d_in[3];
    const float* W_attn  = (const float*)d_in[4];
    const float* W_ffn   = (const float*)d_in[5];
    float* out = (float*)d_out;

    char* ws = (char*)d_ws;
    bf16* normed  = (bf16*)(ws + 0);                    // 16.8 MB (reused as attn_buf)
    bf16* Wd_b    = (bf16*)(ws + 16777216);             // 92.3 MB (reused as q/k/vt after dense)
    bf16* Wa_b    = (bf16*)(ws + 109051904);            // 8.4 MB
    bf16* Wf_b    = (bf16*)(ws + 117440512);            // 33.6 MB
    bf16* h_b     = (bf16*)(ws + 150994944);            // 50.3 MB (qkv, stride 6144)
    bf16* ag_b    = (bf16*)(ws + 335544320);            // 67.1 MB
    float* ctab   = (float*)(ws + 402653184);           // 0.5 MB
    float* stab   = (float*)(ws + 403177472);           // 0.5 MB
    bf16* q_b  = (bf16*)(ws + 16777216);
    bf16* k_b  = (bf16*)(ws + 16777216 + 16777216);
    bf16* vt_b = (bf16*)(ws + 16777216 + 33554432);
    bf16* attn_b = normed;

    cvt_wd<<<46137344/2048, 256, 0, stream>>>(W_dense, Wd_b);
    cvt_f32_bf16<<<4194304/2048, 256, 0, stream>>>(W_attn, Wa_b);
    cvt_f32_bf16<<<16777216/2048, 256, 0, stream>>>(W_ffn, Wf_b);
    rmsnorm_k<<<NROWS, 256, 0, stream>>>(x, g, normed);
    rope_table<<<SEQ*64/256, 256, 0, stream>>>(ctab, stab);
    // dense GEMM -> h6 (qkv) + ag (fused SwiGLU)
    {
        dim3 grid((NROWS/256) * (DOUT/256));            // 1408, %8==0
        gemm_dense<<<grid, 512, 0, stream>>>(normed, Wd_b, b_dense, h_b, ag_b);
    }
    rope_qk<<<4194304/256, 256, 0, stream>>>(h_b, ctab, stab, q_b, k_b);
    {
        dim3 grid(SEQ/64, BATCH*NH);
        v_transpose<<<grid, 256, 0, stream>>>(h_b, vt_b);
    }
    {
        dim3 grid(SEQ/128, BATCH*NH);                   // QBLK=128, 512 blocks
        attn_fa<<<grid, 512, 0, stream>>>(q_b, k_b, vt_b, attn_b);
    }
    gemm_out<<<256, 512, 0, stream>>>(attn_b, Wa_b, ag_b, Wf_b, x, out);
}

// Round 12
// 821.211 us; speedup vs baseline: 1.0119x; 1.0119x over previous
//
#include <hip/hip_runtime.h>
#include <hip/hip_bf16.h>
#include <cmath>

typedef __bf16 bf16;
typedef __attribute__((ext_vector_type(8))) __bf16 bf16x8;
typedef __attribute__((ext_vector_type(4))) float f32x4;
typedef unsigned int u32;
typedef unsigned short u16;

#define D_MODEL 2048
#define NH 16
#define DQ 128
#define DH 2048
#define DFFN 8192
#define DOUT 22528
#define HQKV 6144
#define BATCH 2
#define SEQ 2048
#define NROWS 4096

__device__ __forceinline__ void gload16(const void* g, void* l) {
    __builtin_amdgcn_global_load_lds((__attribute__((address_space(1))) const void*)g,
                                     (__attribute__((address_space(3))) void*)l, 16, 0, 0);
}

__device__ __forceinline__ float bf2f(u16 u) {
    union { u32 i; float f; } c; c.i = ((u32)u) << 16; return c.f;
}

#define VMW(n)  asm volatile("s_waitcnt vmcnt(" #n ")" ::: "memory")
#define LGK0()  asm volatile("s_waitcnt lgkmcnt(0)" ::: "memory")
#define BARX()  { asm volatile("" ::: "memory"); __builtin_amdgcn_s_barrier(); asm volatile("" ::: "memory"); }

// ---------------- W_attn + W_ffn conversion (merged, regions 2048-aligned) ----------------
__global__ __launch_bounds__(256) void cvt_wab(const float* __restrict__ Wa,
                                               const float* __restrict__ Wf,
                                               bf16* __restrict__ WaO,
                                               bf16* __restrict__ WfO) {
    size_t i = ((size_t)blockIdx.x * 256 + threadIdx.x) * 8;
    const float* src;
    bf16* dst;
    if (i < 4194304) { src = Wa + i; dst = WaO + i; }
    else             { src = Wf + (i - 4194304); dst = WfO + (i - 4194304); }
    float4 a = *(const float4*)src;
    float4 b = *(const float4*)(src + 4);
    bf16x8 o;
    o[0]=(bf16)a.x; o[1]=(bf16)a.y; o[2]=(bf16)a.z; o[3]=(bf16)a.w;
    o[4]=(bf16)b.x; o[5]=(bf16)b.y; o[6]=(bf16)b.z; o[7]=(bf16)b.w;
    *(bf16x8*)dst = o;
}

// ---------------- W_dense conversion with gate-interleave row remap (16-col, proven) ----------------
__global__ __launch_bounds__(256) void cvt_wd(const float* __restrict__ in,
                                              bf16* __restrict__ out) {
    size_t i = ((size_t)blockIdx.x * 256 + threadIdx.x) * 8;
    int nr = (int)(i >> 11);
    int c  = (int)(i & 2047);
    int orig;
    if (nr < HQKV) orig = nr;
    else {
        int gg = nr - HQKV;
        int blk = gg >> 4;
        int f = ((blk >> 1) << 4) + (gg & 15);
        orig = (blk & 1) ? (3*DH + DFFN + f) : (3*DH + f);
    }
    const float* src = in + (size_t)orig * 2048 + c;
    float4 a = *(const float4*)src;
    float4 b = *(const float4*)(src + 4);
    bf16x8 o;
    o[0]=(bf16)a.x; o[1]=(bf16)a.y; o[2]=(bf16)a.z; o[3]=(bf16)a.w;
    o[4]=(bf16)b.x; o[5]=(bf16)b.y; o[6]=(bf16)b.z; o[7]=(bf16)b.w;
    *(bf16x8*)(out + i) = o;
}

// ---------------- RMSNorm (fp32 in -> bf16 out) ----------------
__global__ __launch_bounds__(256) void rmsnorm_k(const float* __restrict__ x,
                                                 const float* __restrict__ g,
                                                 bf16* __restrict__ out) {
    __shared__ float red[4];
    const int row = blockIdx.x;
    const int t = threadIdx.x;
    const float* xr = x + (size_t)row * D_MODEL;
    float4 v0 = *(const float4*)(xr + t*8);
    float4 v1 = *(const float4*)(xr + t*8 + 4);
    float ss = v0.x*v0.x + v0.y*v0.y + v0.z*v0.z + v0.w*v0.w
             + v1.x*v1.x + v1.y*v1.y + v1.z*v1.z + v1.w*v1.w;
    #pragma unroll
    for (int m = 32; m >= 1; m >>= 1) ss += __shfl_xor(ss, m);
    if ((t & 63) == 0) red[t >> 6] = ss;
    __syncthreads();
    float tot = red[0] + red[1] + red[2] + red[3];
    float norm = sqrtf(tot) * 0.022097086912079608f;
    float inv = 1.0f / fmaxf(norm, 1e-8f);
    float4 g0 = *(const float4*)(g + t*8);
    float4 g1 = *(const float4*)(g + t*8 + 4);
    bf16x8 o;
    o[0]=(bf16)(v0.x*inv*g0.x); o[1]=(bf16)(v0.y*inv*g0.y);
    o[2]=(bf16)(v0.z*inv*g0.z); o[3]=(bf16)(v0.w*inv*g0.w);
    o[4]=(bf16)(v1.x*inv*g1.x); o[5]=(bf16)(v1.y*inv*g1.y);
    o[6]=(bf16)(v1.z*inv*g1.z); o[7]=(bf16)(v1.w*inv*g1.w);
    *(bf16x8*)(out + (size_t)row * D_MODEL + t*8) = o;
}

// ---------------- RoPE table ----------------
__global__ __launch_bounds__(256) void rope_table(float* __restrict__ ctab,
                                                  float* __restrict__ stab) {
    int idx = blockIdx.x * 256 + threadIdx.x;
    int l = idx >> 6, i = idx & 63;
    float inv = powf(10000.0f, -(float)i / 64.0f);
    float ang = (float)l * inv;
    float s, c;
    sincosf(ang, &s, &c);
    ctab[idx] = c; stab[idx] = s;
}

// ============ 256x256 dense GEMM (R6 2-buffer fine-phase) + fused bias/SwiGLU ============
#define SLINE_A(c_, t_) \
    gload16(Asrc + (size_t)((c_)*64)*2048 + (size_t)(t_)*64, \
            smem + (((t_)&1)<<16) + (c_)*8192 + wid*1024);
#define SLINE_B(c_, t_) \
    gload16(Bsrc + (size_t)((c_)*64)*2048 + (size_t)(t_)*64, \
            smem + (((t_)&1)<<16) + 32768 + (c_)*8192 + wid*1024);

#define PH_READS_B() \
    _Pragma("unroll") for (int n = 0; n < 4; ++n) { \
        const char* p_ = bb + (wn*64 + n*16 + la) * 128; \
        bfr[n][0] = *(const bf16x8*)(p_ + pg0); \
        bfr[n][1] = *(const bf16x8*)(p_ + pg1); }

#define PH_READS_A(qd_) \
    _Pragma("unroll") for (int mm = 0; mm < 2; ++mm) { \
        const char* p_ = ab + (wm*128 + ((qd_)*2 + mm)*16 + la) * 128; \
        af[mm][0] = *(const bf16x8*)(p_ + pg0); \
        af[mm][1] = *(const bf16x8*)(p_ + pg1); }

#define PH_MFMA(qd_) \
    __builtin_amdgcn_s_setprio(1); \
    _Pragma("unroll") for (int mm = 0; mm < 2; ++mm) \
        _Pragma("unroll") for (int n = 0; n < 4; ++n) { \
            acc[(qd_)*2+mm][n] = __builtin_amdgcn_mfma_f32_16x16x32_bf16(af[mm][0], bfr[n][0], acc[(qd_)*2+mm][n], 0, 0, 0); \
            acc[(qd_)*2+mm][n] = __builtin_amdgcn_mfma_f32_16x16x32_bf16(af[mm][1], bfr[n][1], acc[(qd_)*2+mm][n], 0, 0, 0); } \
    __builtin_amdgcn_s_setprio(0);

__global__ __launch_bounds__(512, 2) void gemm_dense(
    const bf16* __restrict__ A, const bf16* __restrict__ B,
    const float* __restrict__ bias, bf16* __restrict__ h6,
    bf16* __restrict__ ag)
{
    __shared__ char smem[131072];              // 2 buf x [A 32KB | B 32KB]
    const int tid = threadIdx.x;
    const int wid = tid >> 6, lane = tid & 63;
    const int la = lane & 15, hi = lane >> 4;
    const int wm = wid >> 2, wn = wid & 3;

    const int nwg = gridDim.x;                 // 1408
    const int cpx = nwg >> 3;                  // 176
    const int bI = blockIdx.x;
    const int wg = (bI & 7) * cpx + (bI >> 3);
    const int bn = wg >> 4, bm = wg & 15;      // bn-major: W panel L2-resident
    const size_t m0 = (size_t)bm * 256, n0 = (size_t)bn * 256;

    const int lr = lane >> 3, lg = lane & 7;
    const int sg = lg ^ lr;
    const bf16* Asrc = A + (m0 + wid*8 + lr) * (size_t)2048 + sg*8;
    const bf16* Bsrc = B + (n0 + wid*8 + lr) * (size_t)2048 + sg*8;

    const int pg0 = (hi ^ (la & 7)) << 4;
    const int pg1 = ((4 + hi) ^ (la & 7)) << 4;

    f32x4 acc[8][4] = {};
    const int NT = 32;                         // 2048/64

    SLINE_A(0,0); SLINE_A(2,0);
    SLINE_B(0,0); SLINE_B(1,0);
    SLINE_B(2,0); SLINE_B(3,0);
    SLINE_A(1,0); SLINE_A(3,0);
    VMW(2);
    BARX();

    bf16x8 bfr[4][2];
    bf16x8 af[2][2];

    #pragma unroll 1
    for (int t = 0; t < NT - 1; ++t) {
        const char* ab = smem + ((t & 1) << 16);
        const char* bb = ab + 32768;
        const int nx = t + 1;
        PH_READS_B(); PH_READS_A(0);
        SLINE_A(0,nx); SLINE_A(2,nx);
        BARX(); LGK0(); PH_MFMA(0); BARX();
        PH_READS_A(1);
        SLINE_B(0,nx); SLINE_B(1,nx);
        BARX(); LGK0(); PH_MFMA(1); VMW(4); BARX();
        PH_READS_A(2);
        SLINE_B(2,nx); SLINE_B(3,nx);
        BARX(); LGK0(); PH_MFMA(2); BARX();
        PH_READS_A(3);
        SLINE_A(1,nx); SLINE_A(3,nx);
        BARX(); LGK0(); PH_MFMA(3); VMW(2); BARX();
    }
    {
        const int t = NT - 1;
        const char* ab = smem + ((t & 1) << 16);
        const char* bb = ab + 32768;
        PH_READS_B(); PH_READS_A(0);
        BARX(); LGK0(); PH_MFMA(0); BARX();
        PH_READS_A(1);
        BARX(); LGK0(); PH_MFMA(1); VMW(0); BARX();
        PH_READS_A(2);
        BARX(); LGK0(); PH_MFMA(2); BARX();
        PH_READS_A(3);
        BARX(); LGK0(); PH_MFMA(3); BARX();
    }

    if (n0 < HQKV) {
        // qkv region -> h6 [4096, 6144] bf16, +bias
        #pragma unroll
        for (int mf = 0; mf < 8; ++mf) {
            const size_t row = m0 + wm*128 + mf*16 + hi*4;
            #pragma unroll
            for (int nf = 0; nf < 4; ++nf) {
                const size_t col = n0 + wn*64 + nf*16 + la;
                const float bv = bias[col];
                #pragma unroll
                for (int r = 0; r < 4; ++r)
                    h6[(row + r) * HQKV + col] = (bf16)(acc[mf][nf][r] + bv);
            }
        }
    } else {
        // gate region (interleaved a|b 16-col blocks, proven map) -> ag [4096, 8192]
        #pragma unroll
        for (int mf = 0; mf < 8; ++mf) {
            const size_t row = m0 + wm*128 + mf*16 + hi*4;
            #pragma unroll
            for (int np = 0; np < 4; np += 2) {
                const int col_a = (int)n0 + wn*64 + np*16 + la;
                const int gg = col_a - HQKV;
                const int f = ((gg >> 5) << 4) + (gg & 15);
                const float ba = bias[3*DH + f];
                const float bb2 = bias[3*DH + DFFN + f];
                #pragma unroll
                for (int r = 0; r < 4; ++r) {
                    float a = acc[mf][np][r] + ba;
                    float b = acc[mf][np+1][r] + bb2;
                    float sil = b / (1.0f + __expf(-b));
                    ag[(row + r) * (size_t)DFFN + f] = (bf16)(a * sil);
                }
            }
        }
    }
}

// ============ fused epilogue GEMM: out = x + attn.Wa^T + ag.Wf^T (bn-major) ============
#define OSTAGE_A(st_, c_) { \
    const bf16* s_ = (st_) < 32 ? A1s + (size_t)((c_)*64)*2048 + (size_t)(st_)*64 \
                                : A2s + (size_t)((c_)*64)*8192 + (size_t)((st_)-32)*64; \
    gload16(s_, smem + ((st_)%3)*49152 + (c_)*8192 + wid*1024); }
#define OSTAGE_B(st_, c_) { \
    const bf16* s_ = (st_) < 32 ? B1s + (size_t)((c_)*64)*2048 + (size_t)(st_)*64 \
                                : B2s + (size_t)((c_)*64)*8192 + (size_t)((st_)-32)*64; \
    gload16(s_, smem + ((st_)%3)*49152 + 16384 + (c_)*8192 + wid*1024); }

__global__ __launch_bounds__(512, 2) void gemm_out(
    const bf16* __restrict__ A1, const bf16* __restrict__ B1,
    const bf16* __restrict__ A2, const bf16* __restrict__ B2,
    const float* __restrict__ x, float* __restrict__ outf)
{
    __shared__ char smem[147456];
    const int tid = threadIdx.x;
    const int wid = tid >> 6, lane = tid & 63;
    const int la = lane & 15, hi = lane >> 4;
    const int wm = wid >> 2, wn = wid & 3;

    const int nwg = gridDim.x;                 // 256
    const int cpx = nwg >> 3;                  // 32
    const int bI = blockIdx.x;
    const int wg = (bI & 7) * cpx + (bI >> 3);
    const int bm = wg & 31, bn = wg >> 5;      // bn-major: B panel L2-resident per XCD
    const size_t m0 = (size_t)bm * 128, n0 = (size_t)bn * 256;

    const int lr = lane >> 3, lg = lane & 7;
    const int sg = lg ^ lr;
    const bf16* A1s = A1 + (m0 + wid*8 + lr) * (size_t)2048 + sg*8;
    const bf16* A2s = A2 + (m0 + wid*8 + lr) * (size_t)8192 + sg*8;
    const bf16* B1s = B1 + (n0 + wid*8 + lr) * (size_t)2048 + sg*8;
    const bf16* B2s = B2 + (n0 + wid*8 + lr) * (size_t)8192 + sg*8;

    const int pg0 = (hi ^ (la & 7)) << 4;
    const int pg1 = ((4 + hi) ^ (la & 7)) << 4;

    f32x4 acc[4][4] = {};
    const int NT = 160;

    OSTAGE_A(0,0); OSTAGE_A(0,1);
    OSTAGE_B(0,0); OSTAGE_B(0,1); OSTAGE_B(0,2); OSTAGE_B(0,3);
    OSTAGE_A(1,0); OSTAGE_A(1,1);
    OSTAGE_B(1,0); OSTAGE_B(1,1); OSTAGE_B(1,2); OSTAGE_B(1,3);
    VMW(6);
    BARX();

    bf16x8 af[4], bfr[4];
    #pragma unroll 1
    for (int t = 0; t < NT; ++t) {
        const char* ab = smem + (t % 3) * 49152;
        const char* bb = ab + 16384;
        const int st = t + 2;
        #pragma unroll
        for (int m = 0; m < 4; ++m) af[m]  = *(const bf16x8*)(ab + (wm*64 + m*16 + la)*128 + pg0);
        #pragma unroll
        for (int n = 0; n < 4; ++n) bfr[n] = *(const bf16x8*)(bb + (wn*64 + n*16 + la)*128 + pg0);
        if (st < NT) { OSTAGE_A(st,0); OSTAGE_A(st,1); OSTAGE_B(st,0); }
        BARX(); LGK0();
        __builtin_amdgcn_s_setprio(1);
        #pragma unroll
        for (int m = 0; m < 4; ++m)
            #pragma unroll
            for (int n = 0; n < 4; ++n)
                acc[m][n] = __builtin_amdgcn_mfma_f32_16x16x32_bf16(af[m], bfr[n], acc[m][n], 0, 0, 0);
        __builtin_amdgcn_s_setprio(0);
        BARX();
        #pragma unroll
        for (int m = 0; m < 4; ++m) af[m]  = *(const bf16x8*)(ab + (wm*64 + m*16 + la)*128 + pg1);
        #pragma unroll
        for (int n = 0; n < 4; ++n) bfr[n] = *(const bf16x8*)(bb + (wn*64 + n*16 + la)*128 + pg1);
        if (st < NT) { OSTAGE_B(st,1); OSTAGE_B(st,2); OSTAGE_B(st,3); }
        if (t < NT - 2) { VMW(6); } else { VMW(0); }
        BARX(); LGK0();
        __builtin_amdgcn_s_setprio(1);
        #pragma unroll
        for (int m = 0; m < 4; ++m)
            #pragma unroll
            for (int n = 0; n < 4; ++n)
                acc[m][n] = __builtin_amdgcn_mfma_f32_16x16x32_bf16(af[m], bfr[n], acc[m][n], 0, 0, 0);
        __builtin_amdgcn_s_setprio(0);
        BARX();
    }

    #pragma unroll
    for (int mf = 0; mf < 4; ++mf) {
        const size_t row = m0 + wm*64 + mf*16 + hi*4;
        #pragma unroll
        for (int nf = 0; nf < 4; ++nf) {
            const size_t col = n0 + wn*64 + nf*16 + la;
            #pragma unroll
            for (int r = 0; r < 4; ++r) {
                const size_t off = (row + r) * (size_t)DH + col;
                outf[off] = x[off] + acc[mf][nf][r];
            }
        }
    }
}

__device__ __forceinline__ u32 rope_pair(u32 u, float c, float s) {
    float t1 = bf2f((u16)(u & 0xffff));
    float t2 = bf2f((u16)(u >> 16));
    float r1 = t1 * c - t2 * s;
    float r2 = t1 * s + t2 * c;
    bf16 b1 = (bf16)r1, b2 = (bf16)r2;
    return (u32)__builtin_bit_cast(u16, b1) | ((u32)__builtin_bit_cast(u16, b2) << 16);
}

// ---------------- fused q/k rope + V transpose (one launch) ----------------
// blocks [0, 16384): rope path; blocks [16384, 17408): v-transpose path.
__global__ __launch_bounds__(256) void qkv_prep(const bf16* __restrict__ h,
                                                const float* __restrict__ ctab,
                                                const float* __restrict__ stab,
                                                bf16* __restrict__ qb, bf16* __restrict__ kb,
                                                bf16* __restrict__ vt) {
    __shared__ u32 lds[64][68];
    const int bid = blockIdx.x;
    const int t = threadIdx.x;
    if (bid < 16384) {
        // ---- rope path (byte-identical logic to proven rope_qk) ----
        int idx = bid * 256 + t;
        int i  = idx & 63;
        int hh = (idx >> 6) & 15;
        int l  = (idx >> 10) & 2047;
        int b  = idx >> 21;
        size_t hrow = (size_t)(b * SEQ + l) * HQKV;
        float c = ctab[l*64 + i], s = stab[l*64 + i];
        u32 uq = *(const u32*)(h + hrow + hh*DQ + 2*i);
        u32 uk = *(const u32*)(h + hrow + DH + hh*DQ + 2*i);
        size_t orow = ((size_t)(b*NH + hh) * SEQ + l) * DQ + 2*i;
        *(u32*)(qb + orow) = rope_pair(uq, c, s);
        *(u32*)(kb + orow) = rope_pair(uk, c, s);
    } else {
        // ---- v-transpose path (byte-identical logic to proven v_transpose) ----
        const int vb = bid - 16384;
        const int lt = vb & 31, bh = vb >> 5;
        const int b = bh >> 4, hh = bh & 15;
        const bf16* src = h + (size_t)(b * SEQ + lt * 64) * HQKV + 2*DH + hh * DQ;
        #pragma unroll
        for (int i = 0; i < 4; ++i) {
            int j = i*256 + t;
            int l = j >> 4, ch = j & 15;
            uint4 v = *(const uint4*)(src + (size_t)l * HQKV + ch*8);
            *(uint4*)&lds[l][ch*4] = v;
        }
        __syncthreads();
        bf16* dst = vt + (size_t)bh * DQ * SEQ + lt * 64;
        #pragma unroll
        for (int i = 0; i < 4; ++i) {
            int j = i*256 + t;
            int d = j >> 3, lc = j & 7;
            u32 out[4];
            #pragma unroll
            for (int m = 0; m < 4; ++m) {
                u32 a0 = lds[lc*8 + 2*m][d >> 1];
                u32 a1 = lds[lc*8 + 2*m + 1][d >> 1];
                u16 s0 = (d & 1) ? (u16)(a0 >> 16) : (u16)(a0 & 0xffff);
                u16 s1 = (d & 1) ? (u16)(a1 >> 16) : (u16)(a1 & 0xffff);
                out[m] = (u32)s0 | ((u32)s1 << 16);
            }
            *(uint4*)(dst + (size_t)d * SEQ + lc*8) = *(uint4*)out;
        }
    }
}

// ---------------- causal flash attention (dbuf K/V, QBLK=64 — R10 proven) ----------------
__global__ __launch_bounds__(256) void attn_fa(const bf16* __restrict__ Q,
                                               const bf16* __restrict__ Kb,
                                               const bf16* __restrict__ Vt,
                                               bf16* __restrict__ O) {
    __shared__ char kvs[2][32768];             // [buf][K 16KB | V 16KB]
    __shared__ bf16 Ps[4][16][64];
    const int qt = blockIdx.x, bh = blockIdx.y;
    const int b = bh >> 4, hh = bh & 15;
    const int tid = threadIdx.x, wid = tid >> 6, lane = tid & 63;
    const int la = lane & 15, hi = lane >> 4;
    const bf16* Qp = Q + (size_t)bh * SEQ * DQ;
    const bf16* Kp = Kb + (size_t)bh * SEQ * DQ;
    const bf16* Vp = Vt + (size_t)bh * DQ * SEQ;
    const int q0w = qt * 64 + wid * 16;

    bf16x8 qf[4];
    #pragma unroll
    for (int s = 0; s < 4; ++s)
        qf[s] = *(const bf16x8*)(Qp + (size_t)(q0w + la) * DQ + s*32 + hi*8);

    f32x4 acc_o[8] = {};
    float m_run[4] = {-1e30f, -1e30f, -1e30f, -1e30f};
    float l_run[4] = {0.f, 0.f, 0.f, 0.f};
    const float scale = 0.08838834764831845f;
    const int nk = qt + 1;

#define ATT_STAGE(kt_, buf_) { \
    const int k0_ = (kt_) * 64; \
    _Pragma("unroll") for (int i = 0; i < 4; ++i) { \
        int j = i*256 + tid; \
        int kr = j >> 4, jg = j & 15; \
        gload16(Kp + (size_t)(k0_ + kr) * DQ + ((jg ^ (kr & 7)) << 3), \
                kvs[buf_] + i*4096 + wid*1024); \
        int d = j >> 3, vg = j & 7; \
        gload16(Vp + (size_t)d * SEQ + k0_ + ((vg ^ (d & 7)) << 3), \
                kvs[buf_] + 16384 + i*4096 + wid*1024); \
    } }

    ATT_STAGE(0, 0);

    for (int kt = 0; kt < nk; ++kt) {
        const int k0 = kt * 64;
        const char* kb2 = kvs[kt & 1];
        if (kt + 1 < nk) { ATT_STAGE(kt+1, (kt+1)&1); VMW(8); }
        else             { VMW(0); }
        BARX();

        f32x4 sacc[4] = {};
        __builtin_amdgcn_s_setprio(1);
        #pragma unroll
        for (int g = 0; g < 4; ++g) {
            const int krow = g*16 + la;
            #pragma unroll
            for (int s = 0; s < 4; ++s) {
                bf16x8 kf = *(const bf16x8*)(kb2 + krow*256 + (((s*4 + hi) ^ (la & 7)) << 4));
                sacc[g] = __builtin_amdgcn_mfma_f32_16x16x32_bf16(qf[s], kf, sacc[g], 0, 0, 0);
            }
        }
        __builtin_amdgcn_s_setprio(0);

        float mnew[4];
        #pragma unroll
        for (int r = 0; r < 4; ++r) mnew[r] = m_run[r];
        #pragma unroll
        for (int g = 0; g < 4; ++g)
            #pragma unroll
            for (int r = 0; r < 4; ++r) {
                float sv = sacc[g][r] * scale;
                int qi = q0w + hi*4 + r;
                int ki = k0 + g*16 + la;
                sv = (ki <= qi) ? sv : -1e30f;
                sacc[g][r] = sv;
                mnew[r] = fmaxf(mnew[r], sv);
            }
        #pragma unroll
        for (int r = 0; r < 4; ++r) {
            float v = mnew[r];
            v = fmaxf(v, __shfl_xor(v, 1));
            v = fmaxf(v, __shfl_xor(v, 2));
            v = fmaxf(v, __shfl_xor(v, 4));
            v = fmaxf(v, __shfl_xor(v, 8));
            mnew[r] = v;
        }
        float resc[4], lsum[4];
        #pragma unroll
        for (int r = 0; r < 4; ++r) {
            resc[r] = __expf(m_run[r] - mnew[r]);
            m_run[r] = mnew[r];
            lsum[r] = 0.f;
        }
        #pragma unroll
        for (int g = 0; g < 4; ++g)
            #pragma unroll
            for (int r = 0; r < 4; ++r) {
                float p = __expf(sacc[g][r] - mnew[r]);
                sacc[g][r] = p;
                lsum[r] += p;
            }
        #pragma unroll
        for (int r = 0; r < 4; ++r) {
            float v = lsum[r];
            v += __shfl_xor(v, 1); v += __shfl_xor(v, 2);
            v += __shfl_xor(v, 4); v += __shfl_xor(v, 8);
            l_run[r] = l_run[r] * resc[r] + v;
        }
        #pragma unroll
        for (int g = 0; g < 4; ++g)
            #pragma unroll
            for (int r = 0; r < 4; ++r) {
                int prow = hi*4 + r;
                int pcol = (g*16 + la) ^ ((prow & 7) << 3);
                Ps[wid][prow][pcol] = (bf16)sacc[g][r];
            }
        #pragma unroll
        for (int n = 0; n < 8; ++n)
            #pragma unroll
            for (int r = 0; r < 4; ++r) acc_o[n][r] *= resc[r];
        __builtin_amdgcn_s_setprio(1);
        #pragma unroll
        for (int kk = 0; kk < 2; ++kk) {
            bf16x8 pf = *(const bf16x8*)((const char*)&Ps[wid][0][0] + la*128 +
                                         (((kk*32 + hi*8) ^ ((la & 7) << 3)) << 1));
            #pragma unroll
            for (int n = 0; n < 8; ++n) {
                const int vrow = n*16 + la;
                bf16x8 vf = *(const bf16x8*)(kb2 + 16384 + vrow*128 + (((kk*4 + hi) ^ (la & 7)) << 4));
                acc_o[n] = __builtin_amdgcn_mfma_f32_16x16x32_bf16(pf, vf, acc_o[n], 0, 0, 0);
            }
        }
        __builtin_amdgcn_s_setprio(0);
        BARX();
    }

    bf16* Op = O + (size_t)b * SEQ * DH + (size_t)hh * DQ;
    #pragma unroll
    for (int r = 0; r < 4; ++r) {
        int qi = q0w + hi*4 + r;
        float invl = 1.0f / l_run[r];
        #pragma unroll
        for (int n = 0; n < 8; ++n)
            Op[(size_t)qi * DH + n*16 + la] = (bf16)(acc_o[n][r] * invl);
    }
}

// ---------------- launch ----------------
extern "C" void kernel_launch(void* const* d_in, const int* in_sizes, int n_in,
                              void* d_out, int out_size, void* d_ws, size_t ws_size,
                              hipStream_t stream) {
    const float* x       = (const float*)d_in[0];
    const float* g       = (const float*)d_in[1];
    const float* W_dense = (const float*)d_in[2];
    const float* b_dense = (const float*)d_in[3];
    const float* W_attn  = (const float*)d_in[4];
    const float* W_ffn   = (const float*)d_in[5];
    float* out = (float*)d_out;

    char* ws = (char*)d_ws;
    bf16* normed  = (bf16*)(ws + 0);                    // 16.8 MB (reused as attn_buf)
    bf16* Wd_b    = (bf16*)(ws + 16777216);             // 92.3 MB (reused as q/k/vt after dense)
    bf16* Wa_b    = (bf16*)(ws + 109051904);            // 8.4 MB
    bf16* Wf_b    = (bf16*)(ws + 117440512);            // 33.6 MB
    bf16* h_b     = (bf16*)(ws + 150994944);            // 50.3 MB (qkv, stride 6144)
    bf16* ag_b    = (bf16*)(ws + 335544320);            // 67.1 MB
    float* ctab   = (float*)(ws + 402653184);           // 0.5 MB
    float* stab   = (float*)(ws + 403177472);           // 0.5 MB
    bf16* q_b  = (bf16*)(ws + 16777216);
    bf16* k_b  = (bf16*)(ws + 16777216 + 16777216);
    bf16* vt_b = (bf16*)(ws + 16777216 + 33554432);
    bf16* attn_b = normed;

    cvt_wd<<<46137344/2048, 256, 0, stream>>>(W_dense, Wd_b);
    cvt_wab<<<20971520/2048, 256, 0, stream>>>(W_attn, W_ffn, Wa_b, Wf_b);
    rmsnorm_k<<<NROWS, 256, 0, stream>>>(x, g, normed);
    rope_table<<<SEQ*64/256, 256, 0, stream>>>(ctab, stab);
    // dense GEMM -> h6 (qkv) + ag (fused SwiGLU)
    {
        dim3 grid((NROWS/256) * (DOUT/256));            // 1408, %8==0
        gemm_dense<<<grid, 512, 0, stream>>>(normed, Wd_b, b_dense, h_b, ag_b);
    }
    // fused rope + v-transpose
    qkv_prep<<<16384 + 1024, 256, 0, stream>>>(h_b, ctab, stab, q_b, k_b, vt_b);
    {
        dim3 grid(SEQ/64, BATCH*NH);
        attn_fa<<<grid, 256, 0, stream>>>(q_b, k_b, vt_b, attn_b);
    }
    gemm_out<<<256, 512, 0, stream>>>(attn_b, Wa_b, ag_b, Wf_b, x, out);
}

// Round 13
// 795.188 us; speedup vs baseline: 1.0450x; 1.0327x over previous
//
#include <hip/hip_runtime.h>
#include <hip/hip_bf16.h>
#include <cmath>

typedef __bf16 bf16;
typedef __attribute__((ext_vector_type(8))) __bf16 bf16x8;
typedef __attribute__((ext_vector_type(4))) float f32x4;
typedef unsigned int u32;
typedef unsigned short u16;

#define D_MODEL 2048
#define NH 16
#define DQ 128
#define DH 2048
#define DFFN 8192
#define DOUT 22528
#define HQKV 6144
#define BATCH 2
#define SEQ 2048
#define NROWS 4096

__device__ __forceinline__ void gload16(const void* g, void* l) {
    __builtin_amdgcn_global_load_lds((__attribute__((address_space(1))) const void*)g,
                                     (__attribute__((address_space(3))) void*)l, 16, 0, 0);
}

__device__ __forceinline__ float bf2f(u16 u) {
    union { u32 i; float f; } c; c.i = ((u32)u) << 16; return c.f;
}

#define VMW(n)  asm volatile("s_waitcnt vmcnt(" #n ")" ::: "memory")
#define LGK0()  asm volatile("s_waitcnt lgkmcnt(0)" ::: "memory")
#define BARX()  { asm volatile("" ::: "memory"); __builtin_amdgcn_s_barrier(); asm volatile("" ::: "memory"); }

// ---------------- W_attn + W_ffn conversion (merged, regions 2048-aligned) ----------------
__global__ __launch_bounds__(256) void cvt_wab(const float* __restrict__ Wa,
                                               const float* __restrict__ Wf,
                                               bf16* __restrict__ WaO,
                                               bf16* __restrict__ WfO) {
    size_t i = ((size_t)blockIdx.x * 256 + threadIdx.x) * 8;
    const float* src;
    bf16* dst;
    if (i < 4194304) { src = Wa + i; dst = WaO + i; }
    else             { src = Wf + (i - 4194304); dst = WfO + (i - 4194304); }
    float4 a = *(const float4*)src;
    float4 b = *(const float4*)(src + 4);
    bf16x8 o;
    o[0]=(bf16)a.x; o[1]=(bf16)a.y; o[2]=(bf16)a.z; o[3]=(bf16)a.w;
    o[4]=(bf16)b.x; o[5]=(bf16)b.y; o[6]=(bf16)b.z; o[7]=(bf16)b.w;
    *(bf16x8*)dst = o;
}

// ---------------- W_dense conversion with gate-interleave row remap (16-col, proven) ----------------
__global__ __launch_bounds__(256) void cvt_wd(const float* __restrict__ in,
                                              bf16* __restrict__ out) {
    size_t i = ((size_t)blockIdx.x * 256 + threadIdx.x) * 8;
    int nr = (int)(i >> 11);
    int c  = (int)(i & 2047);
    int orig;
    if (nr < HQKV) orig = nr;
    else {
        int gg = nr - HQKV;
        int blk = gg >> 4;
        int f = ((blk >> 1) << 4) + (gg & 15);
        orig = (blk & 1) ? (3*DH + DFFN + f) : (3*DH + f);
    }
    const float* src = in + (size_t)orig * 2048 + c;
    float4 a = *(const float4*)src;
    float4 b = *(const float4*)(src + 4);
    bf16x8 o;
    o[0]=(bf16)a.x; o[1]=(bf16)a.y; o[2]=(bf16)a.z; o[3]=(bf16)a.w;
    o[4]=(bf16)b.x; o[5]=(bf16)b.y; o[6]=(bf16)b.z; o[7]=(bf16)b.w;
    *(bf16x8*)(out + i) = o;
}

// ---------------- RMSNorm (fp32 in -> bf16 out) ----------------
__global__ __launch_bounds__(256) void rmsnorm_k(const float* __restrict__ x,
                                                 const float* __restrict__ g,
                                                 bf16* __restrict__ out) {
    __shared__ float red[4];
    const int row = blockIdx.x;
    const int t = threadIdx.x;
    const float* xr = x + (size_t)row * D_MODEL;
    float4 v0 = *(const float4*)(xr + t*8);
    float4 v1 = *(const float4*)(xr + t*8 + 4);
    float ss = v0.x*v0.x + v0.y*v0.y + v0.z*v0.z + v0.w*v0.w
             + v1.x*v1.x + v1.y*v1.y + v1.z*v1.z + v1.w*v1.w;
    #pragma unroll
    for (int m = 32; m >= 1; m >>= 1) ss += __shfl_xor(ss, m);
    if ((t & 63) == 0) red[t >> 6] = ss;
    __syncthreads();
    float tot = red[0] + red[1] + red[2] + red[3];
    float norm = sqrtf(tot) * 0.022097086912079608f;
    float inv = 1.0f / fmaxf(norm, 1e-8f);
    float4 g0 = *(const float4*)(g + t*8);
    float4 g1 = *(const float4*)(g + t*8 + 4);
    bf16x8 o;
    o[0]=(bf16)(v0.x*inv*g0.x); o[1]=(bf16)(v0.y*inv*g0.y);
    o[2]=(bf16)(v0.z*inv*g0.z); o[3]=(bf16)(v0.w*inv*g0.w);
    o[4]=(bf16)(v1.x*inv*g1.x); o[5]=(bf16)(v1.y*inv*g1.y);
    o[6]=(bf16)(v1.z*inv*g1.z); o[7]=(bf16)(v1.w*inv*g1.w);
    *(bf16x8*)(out + (size_t)row * D_MODEL + t*8) = o;
}

// ---------------- RoPE table ----------------
__global__ __launch_bounds__(256) void rope_table(float* __restrict__ ctab,
                                                  float* __restrict__ stab) {
    int idx = blockIdx.x * 256 + threadIdx.x;
    int l = idx >> 6, i = idx & 63;
    float inv = powf(10000.0f, -(float)i / 64.0f);
    float ang = (float)l * inv;
    float s, c;
    sincosf(ang, &s, &c);
    ctab[idx] = c; stab[idx] = s;
}

// ============ 256x256 dense GEMM (R6 2-buffer fine-phase) + fused bias/SwiGLU ============
#define SLINE_A(c_, t_) \
    gload16(Asrc + (size_t)((c_)*64)*2048 + (size_t)(t_)*64, \
            smem + (((t_)&1)<<16) + (c_)*8192 + wid*1024);
#define SLINE_B(c_, t_) \
    gload16(Bsrc + (size_t)((c_)*64)*2048 + (size_t)(t_)*64, \
            smem + (((t_)&1)<<16) + 32768 + (c_)*8192 + wid*1024);

#define PH_READS_B() \
    _Pragma("unroll") for (int n = 0; n < 4; ++n) { \
        const char* p_ = bb + (wn*64 + n*16 + la) * 128; \
        bfr[n][0] = *(const bf16x8*)(p_ + pg0); \
        bfr[n][1] = *(const bf16x8*)(p_ + pg1); }

#define PH_READS_A(qd_) \
    _Pragma("unroll") for (int mm = 0; mm < 2; ++mm) { \
        const char* p_ = ab + (wm*128 + ((qd_)*2 + mm)*16 + la) * 128; \
        af[mm][0] = *(const bf16x8*)(p_ + pg0); \
        af[mm][1] = *(const bf16x8*)(p_ + pg1); }

#define PH_MFMA(qd_) \
    __builtin_amdgcn_s_setprio(1); \
    _Pragma("unroll") for (int mm = 0; mm < 2; ++mm) \
        _Pragma("unroll") for (int n = 0; n < 4; ++n) { \
            acc[(qd_)*2+mm][n] = __builtin_amdgcn_mfma_f32_16x16x32_bf16(af[mm][0], bfr[n][0], acc[(qd_)*2+mm][n], 0, 0, 0); \
            acc[(qd_)*2+mm][n] = __builtin_amdgcn_mfma_f32_16x16x32_bf16(af[mm][1], bfr[n][1], acc[(qd_)*2+mm][n], 0, 0, 0); } \
    __builtin_amdgcn_s_setprio(0);

__global__ __launch_bounds__(512, 2) void gemm_dense(
    const bf16* __restrict__ A, const bf16* __restrict__ B,
    const float* __restrict__ bias, bf16* __restrict__ h6,
    bf16* __restrict__ ag)
{
    __shared__ char smem[131072];              // 2 buf x [A 32KB | B 32KB]
    const int tid = threadIdx.x;
    const int wid = tid >> 6, lane = tid & 63;
    const int la = lane & 15, hi = lane >> 4;
    const int wm = wid >> 2, wn = wid & 3;

    const int nwg = gridDim.x;                 // 1408
    const int cpx = nwg >> 3;                  // 176
    const int bI = blockIdx.x;
    const int wg = (bI & 7) * cpx + (bI >> 3);
    const int bn = wg >> 4, bm = wg & 15;      // bn-major: W panel L2-resident
    const size_t m0 = (size_t)bm * 256, n0 = (size_t)bn * 256;

    const int lr = lane >> 3, lg = lane & 7;
    const int sg = lg ^ lr;
    const bf16* Asrc = A + (m0 + wid*8 + lr) * (size_t)2048 + sg*8;
    const bf16* Bsrc = B + (n0 + wid*8 + lr) * (size_t)2048 + sg*8;

    const int pg0 = (hi ^ (la & 7)) << 4;
    const int pg1 = ((4 + hi) ^ (la & 7)) << 4;

    f32x4 acc[8][4] = {};
    const int NT = 32;                         // 2048/64

    SLINE_A(0,0); SLINE_A(2,0);
    SLINE_B(0,0); SLINE_B(1,0);
    SLINE_B(2,0); SLINE_B(3,0);
    SLINE_A(1,0); SLINE_A(3,0);
    VMW(2);
    BARX();

    bf16x8 bfr[4][2];
    bf16x8 af[2][2];

    #pragma unroll 1
    for (int t = 0; t < NT - 1; ++t) {
        const char* ab = smem + ((t & 1) << 16);
        const char* bb = ab + 32768;
        const int nx = t + 1;
        PH_READS_B(); PH_READS_A(0);
        SLINE_A(0,nx); SLINE_A(2,nx);
        BARX(); LGK0(); PH_MFMA(0); BARX();
        PH_READS_A(1);
        SLINE_B(0,nx); SLINE_B(1,nx);
        BARX(); LGK0(); PH_MFMA(1); VMW(4); BARX();
        PH_READS_A(2);
        SLINE_B(2,nx); SLINE_B(3,nx);
        BARX(); LGK0(); PH_MFMA(2); BARX();
        PH_READS_A(3);
        SLINE_A(1,nx); SLINE_A(3,nx);
        BARX(); LGK0(); PH_MFMA(3); VMW(2); BARX();
    }
    {
        const int t = NT - 1;
        const char* ab = smem + ((t & 1) << 16);
        const char* bb = ab + 32768;
        PH_READS_B(); PH_READS_A(0);
        BARX(); LGK0(); PH_MFMA(0); BARX();
        PH_READS_A(1);
        BARX(); LGK0(); PH_MFMA(1); VMW(0); BARX();
        PH_READS_A(2);
        BARX(); LGK0(); PH_MFMA(2); BARX();
        PH_READS_A(3);
        BARX(); LGK0(); PH_MFMA(3); BARX();
    }

    if (n0 < HQKV) {
        // qkv region -> h6 [4096, 6144] bf16, +bias
        #pragma unroll
        for (int mf = 0; mf < 8; ++mf) {
            const size_t row = m0 + wm*128 + mf*16 + hi*4;
            #pragma unroll
            for (int nf = 0; nf < 4; ++nf) {
                const size_t col = n0 + wn*64 + nf*16 + la;
                const float bv = bias[col];
                #pragma unroll
                for (int r = 0; r < 4; ++r)
                    h6[(row + r) * HQKV + col] = (bf16)(acc[mf][nf][r] + bv);
            }
        }
    } else {
        // gate region (interleaved a|b 16-col blocks, proven map) -> ag [4096, 8192]
        #pragma unroll
        for (int mf = 0; mf < 8; ++mf) {
            const size_t row = m0 + wm*128 + mf*16 + hi*4;
            #pragma unroll
            for (int np = 0; np < 4; np += 2) {
                const int col_a = (int)n0 + wn*64 + np*16 + la;
                const int gg = col_a - HQKV;
                const int f = ((gg >> 5) << 4) + (gg & 15);
                const float ba = bias[3*DH + f];
                const float bb2 = bias[3*DH + DFFN + f];
                #pragma unroll
                for (int r = 0; r < 4; ++r) {
                    float a = acc[mf][np][r] + ba;
                    float b = acc[mf][np+1][r] + bb2;
                    float sil = b / (1.0f + __expf(-b));
                    ag[(row + r) * (size_t)DFFN + f] = (bf16)(a * sil);
                }
            }
        }
    }
}

// ============ fused epilogue GEMM: out = x + attn.Wa^T + ag.Wf^T (bn-major) ============
#define OSTAGE_A(st_, c_) { \
    const bf16* s_ = (st_) < 32 ? A1s + (size_t)((c_)*64)*2048 + (size_t)(st_)*64 \
                                : A2s + (size_t)((c_)*64)*8192 + (size_t)((st_)-32)*64; \
    gload16(s_, smem + ((st_)%3)*49152 + (c_)*8192 + wid*1024); }
#define OSTAGE_B(st_, c_) { \
    const bf16* s_ = (st_) < 32 ? B1s + (size_t)((c_)*64)*2048 + (size_t)(st_)*64 \
                                : B2s + (size_t)((c_)*64)*8192 + (size_t)((st_)-32)*64; \
    gload16(s_, smem + ((st_)%3)*49152 + 16384 + (c_)*8192 + wid*1024); }

__global__ __launch_bounds__(512, 2) void gemm_out(
    const bf16* __restrict__ A1, const bf16* __restrict__ B1,
    const bf16* __restrict__ A2, const bf16* __restrict__ B2,
    const float* __restrict__ x, float* __restrict__ outf)
{
    __shared__ char smem[147456];
    const int tid = threadIdx.x;
    const int wid = tid >> 6, lane = tid & 63;
    const int la = lane & 15, hi = lane >> 4;
    const int wm = wid >> 2, wn = wid & 3;

    const int nwg = gridDim.x;                 // 256
    const int cpx = nwg >> 3;                  // 32
    const int bI = blockIdx.x;
    const int wg = (bI & 7) * cpx + (bI >> 3);
    const int bm = wg & 31, bn = wg >> 5;      // bn-major: B panel L2-resident per XCD
    const size_t m0 = (size_t)bm * 128, n0 = (size_t)bn * 256;

    const int lr = lane >> 3, lg = lane & 7;
    const int sg = lg ^ lr;
    const bf16* A1s = A1 + (m0 + wid*8 + lr) * (size_t)2048 + sg*8;
    const bf16* A2s = A2 + (m0 + wid*8 + lr) * (size_t)8192 + sg*8;
    const bf16* B1s = B1 + (n0 + wid*8 + lr) * (size_t)2048 + sg*8;
    const bf16* B2s = B2 + (n0 + wid*8 + lr) * (size_t)8192 + sg*8;

    const int pg0 = (hi ^ (la & 7)) << 4;
    const int pg1 = ((4 + hi) ^ (la & 7)) << 4;

    f32x4 acc[4][4] = {};
    const int NT = 160;

    OSTAGE_A(0,0); OSTAGE_A(0,1);
    OSTAGE_B(0,0); OSTAGE_B(0,1); OSTAGE_B(0,2); OSTAGE_B(0,3);
    OSTAGE_A(1,0); OSTAGE_A(1,1);
    OSTAGE_B(1,0); OSTAGE_B(1,1); OSTAGE_B(1,2); OSTAGE_B(1,3);
    VMW(6);
    BARX();

    bf16x8 af[4], bfr[4];
    #pragma unroll 1
    for (int t = 0; t < NT; ++t) {
        const char* ab = smem + (t % 3) * 49152;
        const char* bb = ab + 16384;
        const int st = t + 2;
        #pragma unroll
        for (int m = 0; m < 4; ++m) af[m]  = *(const bf16x8*)(ab + (wm*64 + m*16 + la)*128 + pg0);
        #pragma unroll
        for (int n = 0; n < 4; ++n) bfr[n] = *(const bf16x8*)(bb + (wn*64 + n*16 + la)*128 + pg0);
        if (st < NT) { OSTAGE_A(st,0); OSTAGE_A(st,1); OSTAGE_B(st,0); }
        BARX(); LGK0();
        __builtin_amdgcn_s_setprio(1);
        #pragma unroll
        for (int m = 0; m < 4; ++m)
            #pragma unroll
            for (int n = 0; n < 4; ++n)
                acc[m][n] = __builtin_amdgcn_mfma_f32_16x16x32_bf16(af[m], bfr[n], acc[m][n], 0, 0, 0);
        __builtin_amdgcn_s_setprio(0);
        BARX();
        #pragma unroll
        for (int m = 0; m < 4; ++m) af[m]  = *(const bf16x8*)(ab + (wm*64 + m*16 + la)*128 + pg1);
        #pragma unroll
        for (int n = 0; n < 4; ++n) bfr[n] = *(const bf16x8*)(bb + (wn*64 + n*16 + la)*128 + pg1);
        if (st < NT) { OSTAGE_B(st,1); OSTAGE_B(st,2); OSTAGE_B(st,3); }
        if (t < NT - 2) { VMW(6); } else { VMW(0); }
        BARX(); LGK0();
        __builtin_amdgcn_s_setprio(1);
        #pragma unroll
        for (int m = 0; m < 4; ++m)
            #pragma unroll
            for (int n = 0; n < 4; ++n)
                acc[m][n] = __builtin_amdgcn_mfma_f32_16x16x32_bf16(af[m], bfr[n], acc[m][n], 0, 0, 0);
        __builtin_amdgcn_s_setprio(0);
        BARX();
    }

    #pragma unroll
    for (int mf = 0; mf < 4; ++mf) {
        const size_t row = m0 + wm*64 + mf*16 + hi*4;
        #pragma unroll
        for (int nf = 0; nf < 4; ++nf) {
            const size_t col = n0 + wn*64 + nf*16 + la;
            #pragma unroll
            for (int r = 0; r < 4; ++r) {
                const size_t off = (row + r) * (size_t)DH + col;
                outf[off] = x[off] + acc[mf][nf][r];
            }
        }
    }
}

__device__ __forceinline__ u32 rope_pair(u32 u, float c, float s) {
    float t1 = bf2f((u16)(u & 0xffff));
    float t2 = bf2f((u16)(u >> 16));
    float r1 = t1 * c - t2 * s;
    float r2 = t1 * s + t2 * c;
    bf16 b1 = (bf16)r1, b2 = (bf16)r2;
    return (u32)__builtin_bit_cast(u16, b1) | ((u32)__builtin_bit_cast(u16, b2) << 16);
}

// ---------------- fused q/k rope + V transpose (one launch) ----------------
__global__ __launch_bounds__(256) void qkv_prep(const bf16* __restrict__ h,
                                                const float* __restrict__ ctab,
                                                const float* __restrict__ stab,
                                                bf16* __restrict__ qb, bf16* __restrict__ kb,
                                                bf16* __restrict__ vt) {
    __shared__ u32 lds[64][68];
    const int bid = blockIdx.x;
    const int t = threadIdx.x;
    if (bid < 16384) {
        int idx = bid * 256 + t;
        int i  = idx & 63;
        int hh = (idx >> 6) & 15;
        int l  = (idx >> 10) & 2047;
        int b  = idx >> 21;
        size_t hrow = (size_t)(b * SEQ + l) * HQKV;
        float c = ctab[l*64 + i], s = stab[l*64 + i];
        u32 uq = *(const u32*)(h + hrow + hh*DQ + 2*i);
        u32 uk = *(const u32*)(h + hrow + DH + hh*DQ + 2*i);
        size_t orow = ((size_t)(b*NH + hh) * SEQ + l) * DQ + 2*i;
        *(u32*)(qb + orow) = rope_pair(uq, c, s);
        *(u32*)(kb + orow) = rope_pair(uk, c, s);
    } else {
        const int vb = bid - 16384;
        const int lt = vb & 31, bh = vb >> 5;
        const int b = bh >> 4, hh = bh & 15;
        const bf16* src = h + (size_t)(b * SEQ + lt * 64) * HQKV + 2*DH + hh * DQ;
        #pragma unroll
        for (int i = 0; i < 4; ++i) {
            int j = i*256 + t;
            int l = j >> 4, ch = j & 15;
            uint4 v = *(const uint4*)(src + (size_t)l * HQKV + ch*8);
            *(uint4*)&lds[l][ch*4] = v;
        }
        __syncthreads();
        bf16* dst = vt + (size_t)bh * DQ * SEQ + lt * 64;
        #pragma unroll
        for (int i = 0; i < 4; ++i) {
            int j = i*256 + t;
            int d = j >> 3, lc = j & 7;
            u32 out[4];
            #pragma unroll
            for (int m = 0; m < 4; ++m) {
                u32 a0 = lds[lc*8 + 2*m][d >> 1];
                u32 a1 = lds[lc*8 + 2*m + 1][d >> 1];
                u16 s0 = (d & 1) ? (u16)(a0 >> 16) : (u16)(a0 & 0xffff);
                u16 s1 = (d & 1) ? (u16)(a1 >> 16) : (u16)(a1 & 0xffff);
                out[m] = (u32)s0 | ((u32)s1 << 16);
            }
            *(uint4*)(dst + (size_t)d * SEQ + lc*8) = *(uint4*)out;
        }
    }
}

// ---------------- causal flash attention (dbuf K/V, QBLK=64, bh-grouped XCD map) ----------------
// 1D grid 1024: xcd = bid&7, k = bid>>3; bh = xcd*4 + (k>>5), qt = k&31.
// Each XCD's chunk = 4 heads x all qt -> KV (4MB) L2-resident; qt-blocks hit L2 not L3.
__global__ __launch_bounds__(256) void attn_fa(const bf16* __restrict__ Q,
                                               const bf16* __restrict__ Kb,
                                               const bf16* __restrict__ Vt,
                                               bf16* __restrict__ O) {
    __shared__ char kvs[2][32768];             // [buf][K 16KB | V 16KB]
    __shared__ bf16 Ps[4][16][64];
    const int bid = blockIdx.x;
    const int xcd = bid & 7, kk2 = bid >> 3;
    const int bh = xcd * 4 + (kk2 >> 5);
    const int qt = kk2 & 31;
    const int b = bh >> 4, hh = bh & 15;
    const int tid = threadIdx.x, wid = tid >> 6, lane = tid & 63;
    const int la = lane & 15, hi = lane >> 4;
    const bf16* Qp = Q + (size_t)bh * SEQ * DQ;
    const bf16* Kp = Kb + (size_t)bh * SEQ * DQ;
    const bf16* Vp = Vt + (size_t)bh * DQ * SEQ;
    const int q0w = qt * 64 + wid * 16;

    bf16x8 qf[4];
    #pragma unroll
    for (int s = 0; s < 4; ++s)
        qf[s] = *(const bf16x8*)(Qp + (size_t)(q0w + la) * DQ + s*32 + hi*8);

    f32x4 acc_o[8] = {};
    float m_run[4] = {-1e30f, -1e30f, -1e30f, -1e30f};
    float l_run[4] = {0.f, 0.f, 0.f, 0.f};
    const float scale = 0.08838834764831845f;
    const int nk = qt + 1;

#define ATT_STAGE(kt_, buf_) { \
    const int k0_ = (kt_) * 64; \
    _Pragma("unroll") for (int i = 0; i < 4; ++i) { \
        int j = i*256 + tid; \
        int kr = j >> 4, jg = j & 15; \
        gload16(Kp + (size_t)(k0_ + kr) * DQ + ((jg ^ (kr & 7)) << 3), \
                kvs[buf_] + i*4096 + wid*1024); \
        int d = j >> 3, vg = j & 7; \
        gload16(Vp + (size_t)d * SEQ + k0_ + ((vg ^ (d & 7)) << 3), \
                kvs[buf_] + 16384 + i*4096 + wid*1024); \
    } }

    ATT_STAGE(0, 0);

    for (int kt = 0; kt < nk; ++kt) {
        const int k0 = kt * 64;
        const char* kb2 = kvs[kt & 1];
        if (kt + 1 < nk) { ATT_STAGE(kt+1, (kt+1)&1); VMW(8); }
        else             { VMW(0); }
        BARX();

        f32x4 sacc[4] = {};
        __builtin_amdgcn_s_setprio(1);
        #pragma unroll
        for (int g = 0; g < 4; ++g) {
            const int krow = g*16 + la;
            #pragma unroll
            for (int s = 0; s < 4; ++s) {
                bf16x8 kf = *(const bf16x8*)(kb2 + krow*256 + (((s*4 + hi) ^ (la & 7)) << 4));
                sacc[g] = __builtin_amdgcn_mfma_f32_16x16x32_bf16(qf[s], kf, sacc[g], 0, 0, 0);
            }
        }
        __builtin_amdgcn_s_setprio(0);

        float mnew[4];
        #pragma unroll
        for (int r = 0; r < 4; ++r) mnew[r] = m_run[r];
        #pragma unroll
        for (int g = 0; g < 4; ++g)
            #pragma unroll
            for (int r = 0; r < 4; ++r) {
                float sv = sacc[g][r] * scale;
                int qi = q0w + hi*4 + r;
                int ki = k0 + g*16 + la;
                sv = (ki <= qi) ? sv : -1e30f;
                sacc[g][r] = sv;
                mnew[r] = fmaxf(mnew[r], sv);
            }
        #pragma unroll
        for (int r = 0; r < 4; ++r) {
            float v = mnew[r];
            v = fmaxf(v, __shfl_xor(v, 1));
            v = fmaxf(v, __shfl_xor(v, 2));
            v = fmaxf(v, __shfl_xor(v, 4));
            v = fmaxf(v, __shfl_xor(v, 8));
            mnew[r] = v;
        }
        float resc[4], lsum[4];
        #pragma unroll
        for (int r = 0; r < 4; ++r) {
            resc[r] = __expf(m_run[r] - mnew[r]);
            m_run[r] = mnew[r];
            lsum[r] = 0.f;
        }
        #pragma unroll
        for (int g = 0; g < 4; ++g)
            #pragma unroll
            for (int r = 0; r < 4; ++r) {
                float p = __expf(sacc[g][r] - mnew[r]);
                sacc[g][r] = p;
                lsum[r] += p;
            }
        #pragma unroll
        for (int r = 0; r < 4; ++r) {
            float v = lsum[r];
            v += __shfl_xor(v, 1); v += __shfl_xor(v, 2);
            v += __shfl_xor(v, 4); v += __shfl_xor(v, 8);
            l_run[r] = l_run[r] * resc[r] + v;
        }
        #pragma unroll
        for (int g = 0; g < 4; ++g)
            #pragma unroll
            for (int r = 0; r < 4; ++r) {
                int prow = hi*4 + r;
                int pcol = (g*16 + la) ^ ((prow & 7) << 3);
                Ps[wid][prow][pcol] = (bf16)sacc[g][r];
            }
        #pragma unroll
        for (int n = 0; n < 8; ++n)
            #pragma unroll
            for (int r = 0; r < 4; ++r) acc_o[n][r] *= resc[r];
        __builtin_amdgcn_s_setprio(1);
        #pragma unroll
        for (int kk = 0; kk < 2; ++kk) {
            bf16x8 pf = *(const bf16x8*)((const char*)&Ps[wid][0][0] + la*128 +
                                         (((kk*32 + hi*8) ^ ((la & 7) << 3)) << 1));
            #pragma unroll
            for (int n = 0; n < 8; ++n) {
                const int vrow = n*16 + la;
                bf16x8 vf = *(const bf16x8*)(kb2 + 16384 + vrow*128 + (((kk*4 + hi) ^ (la & 7)) << 4));
                acc_o[n] = __builtin_amdgcn_mfma_f32_16x16x32_bf16(pf, vf, acc_o[n], 0, 0, 0);
            }
        }
        __builtin_amdgcn_s_setprio(0);
        BARX();
    }

    bf16* Op = O + (size_t)b * SEQ * DH + (size_t)hh * DQ;
    #pragma unroll
    for (int r = 0; r < 4; ++r) {
        int qi = q0w + hi*4 + r;
        float invl = 1.0f / l_run[r];
        #pragma unroll
        for (int n = 0; n < 8; ++n)
            Op[(size_t)qi * DH + n*16 + la] = (bf16)(acc_o[n][r] * invl);
    }
}

// ---------------- launch ----------------
extern "C" void kernel_launch(void* const* d_in, const int* in_sizes, int n_in,
                              void* d_out, int out_size, void* d_ws, size_t ws_size,
                              hipStream_t stream) {
    const float* x       = (const float*)d_in[0];
    const float* g       = (const float*)d_in[1];
    const float* W_dense = (const float*)d_in[2];
    const float* b_dense = (const float*)d_in[3];
    const float* W_attn  = (const float*)d_in[4];
    const float* W_ffn   = (const float*)d_in[5];
    float* out = (float*)d_out;

    char* ws = (char*)d_ws;
    bf16* normed  = (bf16*)(ws + 0);
    bf16* Wd_b    = (bf16*)(ws + 16777216);
    bf16* Wa_b    = (bf16*)(ws + 109051904);
    bf16* Wf_b    = (bf16*)(ws + 117440512);
    bf16* h_b     = (bf16*)(ws + 150994944);
    bf16* ag_b    = (bf16*)(ws + 335544320);
    float* ctab   = (float*)(ws + 402653184);
    float* stab   = (float*)(ws + 403177472);
    bf16* q_b  = (bf16*)(ws + 16777216);
    bf16* k_b  = (bf16*)(ws + 16777216 + 16777216);
    bf16* vt_b = (bf16*)(ws + 16777216 + 33554432);
    bf16* attn_b = normed;

    cvt_wd<<<46137344/2048, 256, 0, stream>>>(W_dense, Wd_b);
    cvt_wab<<<20971520/2048, 256, 0, stream>>>(W_attn, W_ffn, Wa_b, Wf_b);
    rmsnorm_k<<<NROWS, 256, 0, stream>>>(x, g, normed);
    rope_table<<<SEQ*64/256, 256, 0, stream>>>(ctab, stab);
    {
        dim3 grid((NROWS/256) * (DOUT/256));
        gemm_dense<<<grid, 512, 0, stream>>>(normed, Wd_b, b_dense, h_b, ag_b);
    }
    qkv_prep<<<16384 + 1024, 256, 0, stream>>>(h_b, ctab, stab, q_b, k_b, vt_b);
    attn_fa<<<1024, 256, 0, stream>>>(q_b, k_b, vt_b, attn_b);
    gemm_out<<<256, 512, 0, stream>>>(attn_b, Wa_b, ag_b, Wf_b, x, out);
}

// Round 14
// 777.336 us; speedup vs baseline: 1.0690x; 1.0230x over previous
//
#include <hip/hip_runtime.h>
#include <hip/hip_bf16.h>
#include <cmath>

typedef __bf16 bf16;
typedef __attribute__((ext_vector_type(8))) __bf16 bf16x8;
typedef __attribute__((ext_vector_type(4))) float f32x4;
typedef unsigned int u32;
typedef unsigned short u16;

#define D_MODEL 2048
#define NH 16
#define DQ 128
#define DH 2048
#define DFFN 8192
#define DOUT 22528
#define HQKV 6144
#define BATCH 2
#define SEQ 2048
#define NROWS 4096

__device__ __forceinline__ void gload16(const void* g, void* l) {
    __builtin_amdgcn_global_load_lds((__attribute__((address_space(1))) const void*)g,
                                     (__attribute__((address_space(3))) void*)l, 16, 0, 0);
}

__device__ __forceinline__ float bf2f(u16 u) {
    union { u32 i; float f; } c; c.i = ((u32)u) << 16; return c.f;
}

#define VMW(n)  asm volatile("s_waitcnt vmcnt(" #n ")" ::: "memory")
#define LGK0()  asm volatile("s_waitcnt lgkmcnt(0)" ::: "memory")
#define BARX()  { asm volatile("" ::: "memory"); __builtin_amdgcn_s_barrier(); asm volatile("" ::: "memory"); }

// ---------------- merged preprocessing: cvt_wd + cvt_wa + cvt_wf + rope_table + rmsnorm ----------------
// block ranges (each conv block = 2048 elems):
//   [0, 22528)        : W_dense convert w/ gate-interleave remap
//   [22528, 24576)    : W_attn convert
//   [24576, 32768)    : W_ffn convert
//   [32768, 33280)    : rope table (256 elems/block)
//   [33280, 37376)    : rmsnorm (1 row/block)
__global__ __launch_bounds__(256) void prep(const float* __restrict__ W_dense,
                                            const float* __restrict__ W_attn,
                                            const float* __restrict__ W_ffn,
                                            const float* __restrict__ x,
                                            const float* __restrict__ g,
                                            bf16* __restrict__ WdO,
                                            bf16* __restrict__ WaO,
                                            bf16* __restrict__ WfO,
                                            float* __restrict__ ctab,
                                            float* __restrict__ stab,
                                            bf16* __restrict__ normed) {
    __shared__ float red[4];
    const int bid = blockIdx.x;
    const int t = threadIdx.x;
    if (bid < 32768) {
        // ---- weight conversion paths ----
        const float* src;
        bf16* dst;
        if (bid < 22528) {
            size_t i = ((size_t)bid * 256 + t) * 8;
            int nr = (int)(i >> 11);
            int c  = (int)(i & 2047);
            int orig;
            if (nr < HQKV) orig = nr;
            else {
                int gg = nr - HQKV;
                int blk = gg >> 4;
                int f = ((blk >> 1) << 4) + (gg & 15);
                orig = (blk & 1) ? (3*DH + DFFN + f) : (3*DH + f);
            }
            src = W_dense + (size_t)orig * 2048 + c;
            dst = WdO + i;
        } else if (bid < 24576) {
            size_t i = ((size_t)(bid - 22528) * 256 + t) * 8;
            src = W_attn + i; dst = WaO + i;
        } else {
            size_t i = ((size_t)(bid - 24576) * 256 + t) * 8;
            src = W_ffn + i; dst = WfO + i;
        }
        float4 a = *(const float4*)src;
        float4 b = *(const float4*)(src + 4);
        bf16x8 o;
        o[0]=(bf16)a.x; o[1]=(bf16)a.y; o[2]=(bf16)a.z; o[3]=(bf16)a.w;
        o[4]=(bf16)b.x; o[5]=(bf16)b.y; o[6]=(bf16)b.z; o[7]=(bf16)b.w;
        *(bf16x8*)dst = o;
    } else if (bid < 33280) {
        // ---- rope table ----
        int idx = (bid - 32768) * 256 + t;
        int l = idx >> 6, i = idx & 63;
        float inv = powf(10000.0f, -(float)i / 64.0f);
        float ang = (float)l * inv;
        float s, c;
        sincosf(ang, &s, &c);
        ctab[idx] = c; stab[idx] = s;
    } else {
        // ---- rmsnorm, one row per block ----
        const int row = bid - 33280;
        const float* xr = x + (size_t)row * D_MODEL;
        float4 v0 = *(const float4*)(xr + t*8);
        float4 v1 = *(const float4*)(xr + t*8 + 4);
        float ss = v0.x*v0.x + v0.y*v0.y + v0.z*v0.z + v0.w*v0.w
                 + v1.x*v1.x + v1.y*v1.y + v1.z*v1.z + v1.w*v1.w;
        #pragma unroll
        for (int m = 32; m >= 1; m >>= 1) ss += __shfl_xor(ss, m);
        if ((t & 63) == 0) red[t >> 6] = ss;
        __syncthreads();
        float tot = red[0] + red[1] + red[2] + red[3];
        float norm = sqrtf(tot) * 0.022097086912079608f;
        float inv = 1.0f / fmaxf(norm, 1e-8f);
        float4 g0 = *(const float4*)(g + t*8);
        float4 g1 = *(const float4*)(g + t*8 + 4);
        bf16x8 o;
        o[0]=(bf16)(v0.x*inv*g0.x); o[1]=(bf16)(v0.y*inv*g0.y);
        o[2]=(bf16)(v0.z*inv*g0.z); o[3]=(bf16)(v0.w*inv*g0.w);
        o[4]=(bf16)(v1.x*inv*g1.x); o[5]=(bf16)(v1.y*inv*g1.y);
        o[6]=(bf16)(v1.z*inv*g1.z); o[7]=(bf16)(v1.w*inv*g1.w);
        *(bf16x8*)(normed + (size_t)row * D_MODEL + t*8) = o;
    }
}

// ============ 256x256 dense GEMM (R6 2-buffer fine-phase) + fused bias/SwiGLU ============
#define SLINE_A(c_, t_) \
    gload16(Asrc + (size_t)((c_)*64)*2048 + (size_t)(t_)*64, \
            smem + (((t_)&1)<<16) + (c_)*8192 + wid*1024);
#define SLINE_B(c_, t_) \
    gload16(Bsrc + (size_t)((c_)*64)*2048 + (size_t)(t_)*64, \
            smem + (((t_)&1)<<16) + 32768 + (c_)*8192 + wid*1024);

#define PH_READS_B() \
    _Pragma("unroll") for (int n = 0; n < 4; ++n) { \
        const char* p_ = bb + (wn*64 + n*16 + la) * 128; \
        bfr[n][0] = *(const bf16x8*)(p_ + pg0); \
        bfr[n][1] = *(const bf16x8*)(p_ + pg1); }

#define PH_READS_A(qd_) \
    _Pragma("unroll") for (int mm = 0; mm < 2; ++mm) { \
        const char* p_ = ab + (wm*128 + ((qd_)*2 + mm)*16 + la) * 128; \
        af[mm][0] = *(const bf16x8*)(p_ + pg0); \
        af[mm][1] = *(const bf16x8*)(p_ + pg1); }

#define PH_MFMA(qd_) \
    __builtin_amdgcn_s_setprio(1); \
    _Pragma("unroll") for (int mm = 0; mm < 2; ++mm) \
        _Pragma("unroll") for (int n = 0; n < 4; ++n) { \
            acc[(qd_)*2+mm][n] = __builtin_amdgcn_mfma_f32_16x16x32_bf16(af[mm][0], bfr[n][0], acc[(qd_)*2+mm][n], 0, 0, 0); \
            acc[(qd_)*2+mm][n] = __builtin_amdgcn_mfma_f32_16x16x32_bf16(af[mm][1], bfr[n][1], acc[(qd_)*2+mm][n], 0, 0, 0); } \
    __builtin_amdgcn_s_setprio(0);

__global__ __launch_bounds__(512, 2) void gemm_dense(
    const bf16* __restrict__ A, const bf16* __restrict__ B,
    const float* __restrict__ bias, bf16* __restrict__ h6,
    bf16* __restrict__ ag)
{
    __shared__ char smem[131072];              // 2 buf x [A 32KB | B 32KB]
    const int tid = threadIdx.x;
    const int wid = tid >> 6, lane = tid & 63;
    const int la = lane & 15, hi = lane >> 4;
    const int wm = wid >> 2, wn = wid & 3;

    const int nwg = gridDim.x;                 // 1408
    const int cpx = nwg >> 3;                  // 176
    const int bI = blockIdx.x;
    const int wg = (bI & 7) * cpx + (bI >> 3);
    const int bn = wg >> 4, bm = wg & 15;      // bn-major: W panel L2-resident
    const size_t m0 = (size_t)bm * 256, n0 = (size_t)bn * 256;

    const int lr = lane >> 3, lg = lane & 7;
    const int sg = lg ^ lr;
    const bf16* Asrc = A + (m0 + wid*8 + lr) * (size_t)2048 + sg*8;
    const bf16* Bsrc = B + (n0 + wid*8 + lr) * (size_t)2048 + sg*8;

    const int pg0 = (hi ^ (la & 7)) << 4;
    const int pg1 = ((4 + hi) ^ (la & 7)) << 4;

    f32x4 acc[8][4] = {};
    const int NT = 32;                         // 2048/64

    SLINE_A(0,0); SLINE_A(2,0);
    SLINE_B(0,0); SLINE_B(1,0);
    SLINE_B(2,0); SLINE_B(3,0);
    SLINE_A(1,0); SLINE_A(3,0);
    VMW(2);
    BARX();

    bf16x8 bfr[4][2];
    bf16x8 af[2][2];

    #pragma unroll 1
    for (int t = 0; t < NT - 1; ++t) {
        const char* ab = smem + ((t & 1) << 16);
        const char* bb = ab + 32768;
        const int nx = t + 1;
        PH_READS_B(); PH_READS_A(0);
        SLINE_A(0,nx); SLINE_A(2,nx);
        BARX(); LGK0(); PH_MFMA(0); BARX();
        PH_READS_A(1);
        SLINE_B(0,nx); SLINE_B(1,nx);
        BARX(); LGK0(); PH_MFMA(1); VMW(4); BARX();
        PH_READS_A(2);
        SLINE_B(2,nx); SLINE_B(3,nx);
        BARX(); LGK0(); PH_MFMA(2); BARX();
        PH_READS_A(3);
        SLINE_A(1,nx); SLINE_A(3,nx);
        BARX(); LGK0(); PH_MFMA(3); VMW(2); BARX();
    }
    {
        const int t = NT - 1;
        const char* ab = smem + ((t & 1) << 16);
        const char* bb = ab + 32768;
        PH_READS_B(); PH_READS_A(0);
        BARX(); LGK0(); PH_MFMA(0); BARX();
        PH_READS_A(1);
        BARX(); LGK0(); PH_MFMA(1); VMW(0); BARX();
        PH_READS_A(2);
        BARX(); LGK0(); PH_MFMA(2); BARX();
        PH_READS_A(3);
        BARX(); LGK0(); PH_MFMA(3); BARX();
    }

    if (n0 < HQKV) {
        // qkv region -> h6 [4096, 6144] bf16, +bias
        #pragma unroll
        for (int mf = 0; mf < 8; ++mf) {
            const size_t row = m0 + wm*128 + mf*16 + hi*4;
            #pragma unroll
            for (int nf = 0; nf < 4; ++nf) {
                const size_t col = n0 + wn*64 + nf*16 + la;
                const float bv = bias[col];
                #pragma unroll
                for (int r = 0; r < 4; ++r)
                    h6[(row + r) * HQKV + col] = (bf16)(acc[mf][nf][r] + bv);
            }
        }
    } else {
        // gate region (interleaved a|b 16-col blocks, proven map) -> ag [4096, 8192]
        #pragma unroll
        for (int mf = 0; mf < 8; ++mf) {
            const size_t row = m0 + wm*128 + mf*16 + hi*4;
            #pragma unroll
            for (int np = 0; np < 4; np += 2) {
                const int col_a = (int)n0 + wn*64 + np*16 + la;
                const int gg = col_a - HQKV;
                const int f = ((gg >> 5) << 4) + (gg & 15);
                const float ba = bias[3*DH + f];
                const float bb2 = bias[3*DH + DFFN + f];
                #pragma unroll
                for (int r = 0; r < 4; ++r) {
                    float a = acc[mf][np][r] + ba;
                    float b = acc[mf][np+1][r] + bb2;
                    float sil = b / (1.0f + __expf(-b));
                    ag[(row + r) * (size_t)DFFN + f] = (bf16)(a * sil);
                }
            }
        }
    }
}

// ============ fused epilogue GEMM: out = x + attn.Wa^T + ag.Wf^T (bn-major) ============
#define OSTAGE_A(st_, c_) { \
    const bf16* s_ = (st_) < 32 ? A1s + (size_t)((c_)*64)*2048 + (size_t)(st_)*64 \
                                : A2s + (size_t)((c_)*64)*8192 + (size_t)((st_)-32)*64; \
    gload16(s_, smem + ((st_)%3)*49152 + (c_)*8192 + wid*1024); }
#define OSTAGE_B(st_, c_) { \
    const bf16* s_ = (st_) < 32 ? B1s + (size_t)((c_)*64)*2048 + (size_t)(st_)*64 \
                                : B2s + (size_t)((c_)*64)*8192 + (size_t)((st_)-32)*64; \
    gload16(s_, smem + ((st_)%3)*49152 + 16384 + (c_)*8192 + wid*1024); }

__global__ __launch_bounds__(512, 2) void gemm_out(
    const bf16* __restrict__ A1, const bf16* __restrict__ B1,
    const bf16* __restrict__ A2, const bf16* __restrict__ B2,
    const float* __restrict__ x, float* __restrict__ outf)
{
    __shared__ char smem[147456];
    const int tid = threadIdx.x;
    const int wid = tid >> 6, lane = tid & 63;
    const int la = lane & 15, hi = lane >> 4;
    const int wm = wid >> 2, wn = wid & 3;

    const int nwg = gridDim.x;                 // 256
    const int cpx = nwg >> 3;                  // 32
    const int bI = blockIdx.x;
    const int wg = (bI & 7) * cpx + (bI >> 3);
    const int bm = wg & 31, bn = wg >> 5;      // bn-major: B panel L2-resident per XCD
    const size_t m0 = (size_t)bm * 128, n0 = (size_t)bn * 256;

    const int lr = lane >> 3, lg = lane & 7;
    const int sg = lg ^ lr;
    const bf16* A1s = A1 + (m0 + wid*8 + lr) * (size_t)2048 + sg*8;
    const bf16* A2s = A2 + (m0 + wid*8 + lr) * (size_t)8192 + sg*8;
    const bf16* B1s = B1 + (n0 + wid*8 + lr) * (size_t)2048 + sg*8;
    const bf16* B2s = B2 + (n0 + wid*8 + lr) * (size_t)8192 + sg*8;

    const int pg0 = (hi ^ (la & 7)) << 4;
    const int pg1 = ((4 + hi) ^ (la & 7)) << 4;

    f32x4 acc[4][4] = {};
    const int NT = 160;

    OSTAGE_A(0,0); OSTAGE_A(0,1);
    OSTAGE_B(0,0); OSTAGE_B(0,1); OSTAGE_B(0,2); OSTAGE_B(0,3);
    OSTAGE_A(1,0); OSTAGE_A(1,1);
    OSTAGE_B(1,0); OSTAGE_B(1,1); OSTAGE_B(1,2); OSTAGE_B(1,3);
    VMW(6);
    BARX();

    bf16x8 af[4], bfr[4];
    #pragma unroll 1
    for (int t = 0; t < NT; ++t) {
        const char* ab = smem + (t % 3) * 49152;
        const char* bb = ab + 16384;
        const int st = t + 2;
        #pragma unroll
        for (int m = 0; m < 4; ++m) af[m]  = *(const bf16x8*)(ab + (wm*64 + m*16 + la)*128 + pg0);
        #pragma unroll
        for (int n = 0; n < 4; ++n) bfr[n] = *(const bf16x8*)(bb + (wn*64 + n*16 + la)*128 + pg0);
        if (st < NT) { OSTAGE_A(st,0); OSTAGE_A(st,1); OSTAGE_B(st,0); }
        BARX(); LGK0();
        __builtin_amdgcn_s_setprio(1);
        #pragma unroll
        for (int m = 0; m < 4; ++m)
            #pragma unroll
            for (int n = 0; n < 4; ++n)
                acc[m][n] = __builtin_amdgcn_mfma_f32_16x16x32_bf16(af[m], bfr[n], acc[m][n], 0, 0, 0);
        __builtin_amdgcn_s_setprio(0);
        BARX();
        #pragma unroll
        for (int m = 0; m < 4; ++m) af[m]  = *(const bf16x8*)(ab + (wm*64 + m*16 + la)*128 + pg1);
        #pragma unroll
        for (int n = 0; n < 4; ++n) bfr[n] = *(const bf16x8*)(bb + (wn*64 + n*16 + la)*128 + pg1);
        if (st < NT) { OSTAGE_B(st,1); OSTAGE_B(st,2); OSTAGE_B(st,3); }
        if (t < NT - 2) { VMW(6); } else { VMW(0); }
        BARX(); LGK0();
        __builtin_amdgcn_s_setprio(1);
        #pragma unroll
        for (int m = 0; m < 4; ++m)
            #pragma unroll
            for (int n = 0; n < 4; ++n)
                acc[m][n] = __builtin_amdgcn_mfma_f32_16x16x32_bf16(af[m], bfr[n], acc[m][n], 0, 0, 0);
        __builtin_amdgcn_s_setprio(0);
        BARX();
    }

    #pragma unroll
    for (int mf = 0; mf < 4; ++mf) {
        const size_t row = m0 + wm*64 + mf*16 + hi*4;
        #pragma unroll
        for (int nf = 0; nf < 4; ++nf) {
            const size_t col = n0 + wn*64 + nf*16 + la;
            #pragma unroll
            for (int r = 0; r < 4; ++r) {
                const size_t off = (row + r) * (size_t)DH + col;
                outf[off] = x[off] + acc[mf][nf][r];
            }
        }
    }
}

__device__ __forceinline__ u32 rope_pair(u32 u, float c, float s) {
    float t1 = bf2f((u16)(u & 0xffff));
    float t2 = bf2f((u16)(u >> 16));
    float r1 = t1 * c - t2 * s;
    float r2 = t1 * s + t2 * c;
    bf16 b1 = (bf16)r1, b2 = (bf16)r2;
    return (u32)__builtin_bit_cast(u16, b1) | ((u32)__builtin_bit_cast(u16, b2) << 16);
}

// ---------------- fused q/k rope + V transpose (one launch) ----------------
__global__ __launch_bounds__(256) void qkv_prep(const bf16* __restrict__ h,
                                                const float* __restrict__ ctab,
                                                const float* __restrict__ stab,
                                                bf16* __restrict__ qb, bf16* __restrict__ kb,
                                                bf16* __restrict__ vt) {
    __shared__ u32 lds[64][68];
    const int bid = blockIdx.x;
    const int t = threadIdx.x;
    if (bid < 16384) {
        int idx = bid * 256 + t;
        int i  = idx & 63;
        int hh = (idx >> 6) & 15;
        int l  = (idx >> 10) & 2047;
        int b  = idx >> 21;
        size_t hrow = (size_t)(b * SEQ + l) * HQKV;
        float c = ctab[l*64 + i], s = stab[l*64 + i];
        u32 uq = *(const u32*)(h + hrow + hh*DQ + 2*i);
        u32 uk = *(const u32*)(h + hrow + DH + hh*DQ + 2*i);
        size_t orow = ((size_t)(b*NH + hh) * SEQ + l) * DQ + 2*i;
        *(u32*)(qb + orow) = rope_pair(uq, c, s);
        *(u32*)(kb + orow) = rope_pair(uk, c, s);
    } else {
        const int vb = bid - 16384;
        const int lt = vb & 31, bh = vb >> 5;
        const int b = bh >> 4, hh = bh & 15;
        const bf16* src = h + (size_t)(b * SEQ + lt * 64) * HQKV + 2*DH + hh * DQ;
        #pragma unroll
        for (int i = 0; i < 4; ++i) {
            int j = i*256 + t;
            int l = j >> 4, ch = j & 15;
            uint4 v = *(const uint4*)(src + (size_t)l * HQKV + ch*8);
            *(uint4*)&lds[l][ch*4] = v;
        }
        __syncthreads();
        bf16* dst = vt + (size_t)bh * DQ * SEQ + lt * 64;
        #pragma unroll
        for (int i = 0; i < 4; ++i) {
            int j = i*256 + t;
            int d = j >> 3, lc = j & 7;
            u32 out[4];
            #pragma unroll
            for (int m = 0; m < 4; ++m) {
                u32 a0 = lds[lc*8 + 2*m][d >> 1];
                u32 a1 = lds[lc*8 + 2*m + 1][d >> 1];
                u16 s0 = (d & 1) ? (u16)(a0 >> 16) : (u16)(a0 & 0xffff);
                u16 s1 = (d & 1) ? (u16)(a1 >> 16) : (u16)(a1 & 0xffff);
                out[m] = (u32)s0 | ((u32)s1 << 16);
            }
            *(uint4*)(dst + (size_t)d * SEQ + lc*8) = *(uint4*)out;
        }
    }
}

// ---------------- causal flash attention (dbuf K/V, QBLK=64, bh-grouped XCD map, longest-first) ----------------
// 1D grid 1024: xcd = bid&7, k = bid>>3; bh = xcd*4 + (k>>5), qt = 31 - (k&31).
// Longest (qt=31) blocks dispatch first -> better tail packing.
__global__ __launch_bounds__(256) void attn_fa(const bf16* __restrict__ Q,
                                               const bf16* __restrict__ Kb,
                                               const bf16* __restrict__ Vt,
                                               bf16* __restrict__ O) {
    __shared__ char kvs[2][32768];             // [buf][K 16KB | V 16KB]
    __shared__ bf16 Ps[4][16][64];
    const int bid = blockIdx.x;
    const int xcd = bid & 7, kk2 = bid >> 3;
    const int bh = xcd * 4 + (kk2 >> 5);
    const int qt = 31 - (kk2 & 31);
    const int b = bh >> 4, hh = bh & 15;
    const int tid = threadIdx.x, wid = tid >> 6, lane = tid & 63;
    const int la = lane & 15, hi = lane >> 4;
    const bf16* Qp = Q + (size_t)bh * SEQ * DQ;
    const bf16* Kp = Kb + (size_t)bh * SEQ * DQ;
    const bf16* Vp = Vt + (size_t)bh * DQ * SEQ;
    const int q0w = qt * 64 + wid * 16;

    bf16x8 qf[4];
    #pragma unroll
    for (int s = 0; s < 4; ++s)
        qf[s] = *(const bf16x8*)(Qp + (size_t)(q0w + la) * DQ + s*32 + hi*8);

    f32x4 acc_o[8] = {};
    float m_run[4] = {-1e30f, -1e30f, -1e30f, -1e30f};
    float l_run[4] = {0.f, 0.f, 0.f, 0.f};
    const float scale = 0.08838834764831845f;
    const int nk = qt + 1;

#define ATT_STAGE(kt_, buf_) { \
    const int k0_ = (kt_) * 64; \
    _Pragma("unroll") for (int i = 0; i < 4; ++i) { \
        int j = i*256 + tid; \
        int kr = j >> 4, jg = j & 15; \
        gload16(Kp + (size_t)(k0_ + kr) * DQ + ((jg ^ (kr & 7)) << 3), \
                kvs[buf_] + i*4096 + wid*1024); \
        int d = j >> 3, vg = j & 7; \
        gload16(Vp + (size_t)d * SEQ + k0_ + ((vg ^ (d & 7)) << 3), \
                kvs[buf_] + 16384 + i*4096 + wid*1024); \
    } }

    ATT_STAGE(0, 0);

    for (int kt = 0; kt < nk; ++kt) {
        const int k0 = kt * 64;
        const char* kb2 = kvs[kt & 1];
        if (kt + 1 < nk) { ATT_STAGE(kt+1, (kt+1)&1); VMW(8); }
        else             { VMW(0); }
        BARX();

        f32x4 sacc[4] = {};
        __builtin_amdgcn_s_setprio(1);
        #pragma unroll
        for (int g = 0; g < 4; ++g) {
            const int krow = g*16 + la;
            #pragma unroll
            for (int s = 0; s < 4; ++s) {
                bf16x8 kf = *(const bf16x8*)(kb2 + krow*256 + (((s*4 + hi) ^ (la & 7)) << 4));
                sacc[g] = __builtin_amdgcn_mfma_f32_16x16x32_bf16(qf[s], kf, sacc[g], 0, 0, 0);
            }
        }
        __builtin_amdgcn_s_setprio(0);

        float mnew[4];
        #pragma unroll
        for (int r = 0; r < 4; ++r) mnew[r] = m_run[r];
        #pragma unroll
        for (int g = 0; g < 4; ++g)
            #pragma unroll
            for (int r = 0; r < 4; ++r) {
                float sv = sacc[g][r] * scale;
                int qi = q0w + hi*4 + r;
                int ki = k0 + g*16 + la;
                sv = (ki <= qi) ? sv : -1e30f;
                sacc[g][r] = sv;
                mnew[r] = fmaxf(mnew[r], sv);
            }
        #pragma unroll
        for (int r = 0; r < 4; ++r) {
            float v = mnew[r];
            v = fmaxf(v, __shfl_xor(v, 1));
            v = fmaxf(v, __shfl_xor(v, 2));
            v = fmaxf(v, __shfl_xor(v, 4));
            v = fmaxf(v, __shfl_xor(v, 8));
            mnew[r] = v;
        }
        float resc[4], lsum[4];
        #pragma unroll
        for (int r = 0; r < 4; ++r) {
            resc[r] = __expf(m_run[r] - mnew[r]);
            m_run[r] = mnew[r];
            lsum[r] = 0.f;
        }
        #pragma unroll
        for (int g = 0; g < 4; ++g)
            #pragma unroll
            for (int r = 0; r < 4; ++r) {
                float p = __expf(sacc[g][r] - mnew[r]);
                sacc[g][r] = p;
                lsum[r] += p;
            }
        #pragma unroll
        for (int r = 0; r < 4; ++r) {
            float v = lsum[r];
            v += __shfl_xor(v, 1); v += __shfl_xor(v, 2);
            v += __shfl_xor(v, 4); v += __shfl_xor(v, 8);
            l_run[r] = l_run[r] * resc[r] + v;
        }
        #pragma unroll
        for (int g = 0; g < 4; ++g)
            #pragma unroll
            for (int r = 0; r < 4; ++r) {
                int prow = hi*4 + r;
                int pcol = (g*16 + la) ^ ((prow & 7) << 3);
                Ps[wid][prow][pcol] = (bf16)sacc[g][r];
            }
        #pragma unroll
        for (int n = 0; n < 8; ++n)
            #pragma unroll
            for (int r = 0; r < 4; ++r) acc_o[n][r] *= resc[r];
        __builtin_amdgcn_s_setprio(1);
        #pragma unroll
        for (int kk = 0; kk < 2; ++kk) {
            bf16x8 pf = *(const bf16x8*)((const char*)&Ps[wid][0][0] + la*128 +
                                         (((kk*32 + hi*8) ^ ((la & 7) << 3)) << 1));
            #pragma unroll
            for (int n = 0; n < 8; ++n) {
                const int vrow = n*16 + la;
                bf16x8 vf = *(const bf16x8*)(kb2 + 16384 + vrow*128 + (((kk*4 + hi) ^ (la & 7)) << 4));
                acc_o[n] = __builtin_amdgcn_mfma_f32_16x16x32_bf16(pf, vf, acc_o[n], 0, 0, 0);
            }
        }
        __builtin_amdgcn_s_setprio(0);
        BARX();
    }

    bf16* Op = O + (size_t)b * SEQ * DH + (size_t)hh * DQ;
    #pragma unroll
    for (int r = 0; r < 4; ++r) {
        int qi = q0w + hi*4 + r;
        float invl = 1.0f / l_run[r];
        #pragma unroll
        for (int n = 0; n < 8; ++n)
            Op[(size_t)qi * DH + n*16 + la] = (bf16)(acc_o[n][r] * invl);
    }
}

// ---------------- launch ----------------
extern "C" void kernel_launch(void* const* d_in, const int* in_sizes, int n_in,
                              void* d_out, int out_size, void* d_ws, size_t ws_size,
                              hipStream_t stream) {
    const float* x       = (const float*)d_in[0];
    const float* g       = (const float*)d_in[1];
    const float* W_dense = (const float*)d_in[2];
    const float* b_dense = (const float*)d_in[3];
    const float* W_attn  = (const float*)d_in[4];
    const float* W_ffn   = (const float*)d_in[5];
    float* out = (float*)d_out;

    char* ws = (char*)d_ws;
    bf16* normed  = (bf16*)(ws + 0);
    bf16* Wd_b    = (bf16*)(ws + 16777216);
    bf16* Wa_b    = (bf16*)(ws + 109051904);
    bf16* Wf_b    = (bf16*)(ws + 117440512);
    bf16* h_b     = (bf16*)(ws + 150994944);
    bf16* ag_b    = (bf16*)(ws + 335544320);
    float* ctab   = (float*)(ws + 402653184);
    float* stab   = (float*)(ws + 403177472);
    bf16* q_b  = (bf16*)(ws + 16777216);
    bf16* k_b  = (bf16*)(ws + 16777216 + 16777216);
    bf16* vt_b = (bf16*)(ws + 16777216 + 33554432);
    bf16* attn_b = normed;

    // merged preprocessing: all conversions + rope table + rmsnorm
    prep<<<37376, 256, 0, stream>>>(W_dense, W_attn, W_ffn, x, g,
                                    Wd_b, Wa_b, Wf_b, ctab, stab, normed);
    {
        dim3 grid((NROWS/256) * (DOUT/256));
        gemm_dense<<<grid, 512, 0, stream>>>(normed, Wd_b, b_dense, h_b, ag_b);
    }
    qkv_prep<<<16384 + 1024, 256, 0, stream>>>(h_b, ctab, stab, q_b, k_b, vt_b);
    attn_fa<<<1024, 256, 0, stream>>>(q_b, k_b, vt_b, attn_b);
    gemm_out<<<256, 512, 0, stream>>>(attn_b, Wa_b, ag_b, Wf_b, x, out);
}